// Round 12
// baseline (1960.923 us; speedup 1.0000x reference)
//
#include <hip/hip_runtime.h>

// Problem dims
#define B_N 4096
#define V_N 2000
#define K_N 50
#define H_N 500
#define E_N 300
#define VP  2048   // padded vocab (mult of 32 for MFMA k)
#define TP  64     // padded topics
#define SK_NWG 128
#define SK_ITER 500
#define SLOT_E (TP * VP)   // ushort elements per rotation slot (256 KB)

typedef short bf16x8 __attribute__((ext_vector_type(8)));
typedef float f32x4n __attribute__((ext_vector_type(4)));

__device__ __forceinline__ unsigned short f2bf(float f) {
  unsigned int x = __float_as_uint(f);
  x = (x + 0x7FFFu + ((x >> 16) & 1u)) >> 16;
  return (unsigned short)x;
}
__device__ __forceinline__ float bf2f(unsigned short h) {
  return __uint_as_float((unsigned int)h << 16);
}
__device__ __forceinline__ float softplusf(float x) {
  return fmaxf(x, 0.f) + log1pf(expf(-fabsf(x)));
}

// Agent-coherent 8B store (write-through to the coherence point).
__device__ __forceinline__ void coh_store8(unsigned short* p, ushort4 val) {
  union { ushort4 s; unsigned long long u; } cvt; cvt.s = val;
  __hip_atomic_store((unsigned long long*)p, cvt.u,
                     __ATOMIC_RELAXED, __HIP_MEMORY_SCOPE_AGENT);
}

// R18: bijective chunked XCD swizzle (kept; small but positive).
__device__ __forceinline__ void xcd_swizzle(int& bx, int& by, int& bz) {
  const int gx = (int)gridDim.x, gy = (int)gridDim.y;
  const int NB = gx * gy * (int)gridDim.z;
  const int lin = (int)blockIdx.x + gx * ((int)blockIdx.y + gy * (int)blockIdx.z);
  const int chunk = NB >> 3;
  const int lp = (lin & 7) * chunk + (lin >> 3);
  bx = lp % gx;
  const int tmp = lp / gx;
  by = tmp % gy;
  bz = tmp / gy;
}

// ---------------------------------------------------------------------------
// 64-tile fp32 GEMM body. R19: BK 16 -> 32. Halves barrier count and doubles
// the FMA run per stage (512 FMAs between barriers) -- the BK=16 loop was
// barrier/LDS-latency-limited. LDS 2x(32x68)x2x4B = 34.8 KB -> still 4 WGs/CU
// (occupancy preserved; R16 lesson). Per-output k-order still ascending with
// exact-no-op guards -> BIT-IDENTICAL. LDS dbuf + register prefetch +
// sched_barrier (R15-proven).
// ---------------------------------------------------------------------------
__device__ __forceinline__ void gemm_tile_body(
    const float* __restrict__ A, const float* __restrict__ Bm,
    const float* __restrict__ bias, void* __restrict__ Cv,
    int M, int N, int Kd, int act, int bf16out, int bx, int by,
    float (*As)[32][68], float (*Bs)[32][68]) {
  const int tid = threadIdx.x;
  const int tx = tid & 15, ty = tid >> 4;
  const int row0 = by * 64, col0 = bx * 64;
  float acc[4][4];
#pragma unroll
  for (int i = 0; i < 4; ++i)
#pragma unroll
    for (int j = 0; j < 4; ++j) acc[i][j] = 0.f;

  float pa[8], pb[8];
  // prologue: tile 0 (k = 0..31)
#pragma unroll
  for (int i = 0; i < 8; ++i) {
    int id = tid + 256 * i;
    int m = id >> 5, kk = id & 31;
    int gr = row0 + m;
    pa[i] = (gr < M && kk < Kd) ? A[(size_t)gr * Kd + kk] : 0.f;
  }
#pragma unroll
  for (int i = 0; i < 8; ++i) {
    int id = tid + 256 * i;
    int kk = id >> 6, n = id & 63;
    int gc = col0 + n;
    pb[i] = (kk < Kd && gc < N) ? Bm[(size_t)kk * N + gc] : 0.f;
  }
#pragma unroll
  for (int i = 0; i < 8; ++i) { int id = tid + 256 * i; As[0][id & 31][id >> 5] = pa[i]; }
#pragma unroll
  for (int i = 0; i < 8; ++i) { int id = tid + 256 * i; Bs[0][id >> 6][id & 63] = pb[i]; }
  __syncthreads();

  const int nt = (Kd + 31) >> 5;
  for (int t = 1; t < nt; ++t) {
    const int k0 = t << 5;
#pragma unroll
    for (int i = 0; i < 8; ++i) {
      int id = tid + 256 * i;
      int m = id >> 5, kk = id & 31;
      int gr = row0 + m, gk = k0 + kk;
      pa[i] = (gr < M && gk < Kd) ? A[(size_t)gr * Kd + gk] : 0.f;
    }
#pragma unroll
    for (int i = 0; i < 8; ++i) {
      int id = tid + 256 * i;
      int kk = id >> 6, n = id & 63;
      int gk = k0 + kk, gc = col0 + n;
      pb[i] = (gk < Kd && gc < N) ? Bm[(size_t)gk * N + gc] : 0.f;
    }
    __builtin_amdgcn_sched_barrier(0);   // keep prefetch issued above FMAs
    const int cb = (t - 1) & 1;
#pragma unroll
    for (int kk = 0; kk < 32; ++kk) {
      float4 av = *(const float4*)&As[cb][kk][ty * 4];
      float4 bv = *(const float4*)&Bs[cb][kk][tx * 4];
      float aa[4] = {av.x, av.y, av.z, av.w};
      float bb[4] = {bv.x, bv.y, bv.z, bv.w};
#pragma unroll
      for (int i = 0; i < 4; ++i)
#pragma unroll
        for (int j = 0; j < 4; ++j) acc[i][j] = fmaf(aa[i], bb[j], acc[i][j]);
    }
    const int wb = t & 1;
#pragma unroll
    for (int i = 0; i < 8; ++i) { int id = tid + 256 * i; As[wb][id & 31][id >> 5] = pa[i]; }
#pragma unroll
    for (int i = 0; i < 8; ++i) { int id = tid + 256 * i; Bs[wb][id >> 6][id & 63] = pb[i]; }
    __syncthreads();
  }
  const int lb = (nt - 1) & 1;
#pragma unroll
  for (int kk = 0; kk < 32; ++kk) {
    float4 av = *(const float4*)&As[lb][kk][ty * 4];
    float4 bv = *(const float4*)&Bs[lb][kk][tx * 4];
    float aa[4] = {av.x, av.y, av.z, av.w};
    float bb[4] = {bv.x, bv.y, bv.z, bv.w};
#pragma unroll
    for (int i = 0; i < 4; ++i)
#pragma unroll
      for (int j = 0; j < 4; ++j) acc[i][j] = fmaf(aa[i], bb[j], acc[i][j]);
  }
#pragma unroll
  for (int i = 0; i < 4; ++i) {
    int row = row0 + ty * 4 + i;
    if (row >= M) continue;
#pragma unroll
    for (int j = 0; j < 4; ++j) {
      int col = col0 + tx * 4 + j;
      if (col >= N) continue;
      float v = acc[i][j] + (bias ? bias[col] : 0.f);
      if (act) v = softplusf(v);
      if (bf16out) ((unsigned short*)Cv)[(size_t)row * N + col] = f2bf(v);
      else         ((float*)Cv)[(size_t)row * N + col] = v;
    }
  }
}

// 2-way (z picks side a/b), XCD-swizzled
__global__ __launch_bounds__(256) void gemm_nn2_kern(
    const float* A0, const float* B0, const float* b0, void* C0,
    const float* A1, const float* B1, const float* b1, void* C1,
    int M, int N, int Kd, int act, int bf16out) {
  __shared__ float As[2][32][68];
  __shared__ float Bs[2][32][68];
  int bx, by, bz;
  xcd_swizzle(bx, by, bz);
  gemm_tile_body(bz ? A1 : A0, bz ? B1 : B0, bz ? b1 : b0, bz ? C1 : C0,
                 M, N, Kd, act, bf16out, bx, by, As, Bs);
}

// 4-way (mu_a, lv_a, mu_b, lv_b), XCD-swizzled
__global__ __launch_bounds__(256) void gemm_nn4_kern(
    const float* A0, const float* B0, const float* b0, void* C0,
    const float* A1, const float* B1, const float* b1, void* C1,
    const float* A2, const float* B2, const float* b2, void* C2,
    const float* A3, const float* B3, const float* b3, void* C3,
    int M, int N, int Kd, int act, int bf16out) {
  __shared__ float As[2][32][68];
  __shared__ float Bs[2][32][68];
  int bx, by, bz;
  xcd_swizzle(bx, by, bz);
  const float* A = (bz == 0) ? A0 : (bz == 1) ? A1 : (bz == 2) ? A2 : A3;
  const float* B = (bz == 0) ? B0 : (bz == 1) ? B1 : (bz == 2) ? B2 : B3;
  const float* bb = (bz == 0) ? b0 : (bz == 1) ? b1 : (bz == 2) ? b2 : b3;
  void* C = (bz == 0) ? C0 : (bz == 1) ? C1 : (bz == 2) ? C2 : C3;
  gemm_tile_body(A, B, bb, C, M, N, Kd, act, bf16out, bx, by, As, Bs);
}

// ---------------------------------------------------------------------------
// Column partial sums (BN stats) -- 4-way / 2-way fused
// ---------------------------------------------------------------------------
__global__ void colstats4_kern(
    const float* X0, const float* X1, const float* X2, const float* X3,
    int C, int rowsPer, float* __restrict__ sums, float* __restrict__ sumsq) {
  const int z = blockIdx.z;
  const float* X = (z == 0) ? X0 : (z == 1) ? X1 : (z == 2) ? X2 : X3;
  float* s_ = sums + (size_t)z * 2048;
  float* q_ = sumsq + (size_t)z * 2048;
  int c = (int)blockIdx.x * 256 + threadIdx.x;
  if (c >= C) return;
  int r0 = (int)blockIdx.y * rowsPer;
  float s = 0.f, s2 = 0.f;
  for (int r = r0; r < r0 + rowsPer; ++r) {
    float v = X[(size_t)r * C + c];
    s += v; s2 += v * v;
  }
  atomicAdd(&s_[c], s);
  atomicAdd(&q_[c], s2);
}

__global__ void colstats_bf2_kern(
    const unsigned short* X0, const unsigned short* X1,
    int C, int rowsPer, float* __restrict__ sums, float* __restrict__ sumsq) {
  const int z = blockIdx.z;
  const unsigned short* X = z ? X1 : X0;
  float* s_ = sums + (size_t)z * 2048;
  float* q_ = sumsq + (size_t)z * 2048;
  int c = (int)blockIdx.x * 256 + threadIdx.x;
  if (c >= C) return;
  int r0 = (int)blockIdx.y * rowsPer;
  float s = 0.f, s2 = 0.f;
  for (int r = r0; r < r0 + rowsPer; ++r) {
    float v = bf2f(X[(size_t)r * C + c]);
    s += v; s2 += v * v;
  }
  atomicAdd(&s_[c], s);
  atomicAdd(&q_[c], s2);
}

__global__ void finstats_kern(const float* __restrict__ sums, const float* __restrict__ sumsq,
                              int C, float invM, float* __restrict__ mean,
                              float* __restrict__ rstd) {
  int c = (int)blockIdx.x * 256 + threadIdx.x;
  if (c >= C) return;
  float mu = sums[c] * invM;
  float var = sumsq[c] * invM - mu * mu;
  mean[c] = mu;
  rstd[c] = rsqrtf(var + 1e-5f);
}

// ---------------------------------------------------------------------------
// BN-apply + reparam + row-softmax(50) -> theta ; accumulate KLD (2-way)
// ---------------------------------------------------------------------------
__global__ __launch_bounds__(256) void reparam2_kern(
    const float* __restrict__ MU0, const float* __restrict__ LV0,
    const float* __restrict__ MU1, const float* __restrict__ LV1,
    const float* __restrict__ mean4, const float* __restrict__ rstd4,
    const float* __restrict__ mbn0, const float* __restrict__ lbn0,
    const float* __restrict__ mbn1, const float* __restrict__ lbn1,
    const float* __restrict__ eps0, const float* __restrict__ eps1,
    float* __restrict__ TH0, float* __restrict__ TH1,
    float* __restrict__ accp) {
  const int z = blockIdx.z;
  const float* MUp = z ? MU1 : MU0;
  const float* LVp = z ? LV1 : LV0;
  const float* mmean = mean4 + (size_t)(z * 2) * 2048;
  const float* mrstd = rstd4 + (size_t)(z * 2) * 2048;
  const float* lmean = mean4 + (size_t)(z * 2 + 1) * 2048;
  const float* lrstd = rstd4 + (size_t)(z * 2 + 1) * 2048;
  const float* mbn = z ? mbn1 : mbn0;
  const float* lbn = z ? lbn1 : lbn0;
  const float* epsb = z ? eps1 : eps0;
  float* TH = z ? TH1 : TH0;

  const int wave = threadIdx.x >> 6, lane = threadIdx.x & 63;
  const int row = (int)blockIdx.x * 4 + wave;
  const bool act = lane < K_N;
  float mu = 0.f, lv = 0.f, zz = 0.f;
  size_t base = (size_t)row * K_N + lane;
  if (act) {
    mu = (MUp[base] - mmean[lane]) * mrstd[lane] + mbn[lane];
    lv = (LVp[base] - lmean[lane]) * lrstd[lane] + lbn[lane];
    zz = mu + expf(0.5f * lv) * epsb[base];
  }
  float zm = act ? zz : -1e30f;
#pragma unroll
  for (int m = 32; m; m >>= 1) zm = fmaxf(zm, __shfl_xor(zm, m));
  float e = act ? expf(zz - zm) : 0.f;
  float se = e;
#pragma unroll
  for (int m = 32; m; m >>= 1) se += __shfl_xor(se, m);
  if (act) TH[base] = e / se;
  float kt = 0.f;
  if (act) {
    float var = expf(lv);
    kt = var * (1.f / 0.98f) + mu * mu * (1.f / 0.98f) + logf(0.98f) - lv;
  }
  float sk = kt;
#pragma unroll
  for (int m = 32; m; m >>= 1) sk += __shfl_xor(sk, m);
  if (lane == 0) atomicAdd(accp + z, 0.5f * (sk - (float)K_N));
}

// ---------------------------------------------------------------------------
// decode: BN-apply + row softmax + rec; one block/row (2-way), single pass.
// ---------------------------------------------------------------------------
__global__ __launch_bounds__(256) void decode_rec2_kern(
    const unsigned short* __restrict__ D0, const unsigned short* __restrict__ D1,
    const float* __restrict__ mean2, const float* __restrict__ rstd2,
    const float* __restrict__ bias0, const float* __restrict__ bias1,
    const float* __restrict__ X0, const float* __restrict__ X1,
    float* __restrict__ accp) {
  __shared__ float sred[256];
  const int z = blockIdx.z;
  const unsigned short* DECb = z ? D1 : D0;
  const float* mean = mean2 + (size_t)z * 2048;
  const float* rstd = rstd2 + (size_t)z * 2048;
  const float* bias = z ? bias1 : bias0;
  const float* X = z ? X1 : X0;
  const int row = (int)blockIdx.x, tid = threadIdx.x;
  const size_t base = (size_t)row * V_N;

  float yv[8];
  float mx = -1e30f;
#pragma unroll
  for (int it = 0; it < 8; ++it) {
    int j = tid + it * 256;
    float y = -1e30f;
    if (j < V_N) y = (bf2f(DECb[base + j]) - mean[j]) * rstd[j] + bias[j];
    yv[it] = y;
    mx = fmaxf(mx, y);
  }
  sred[tid] = mx; __syncthreads();
  for (int s = 128; s; s >>= 1) { if (tid < s) sred[tid] = fmaxf(sred[tid], sred[tid + s]); __syncthreads(); }
  mx = sred[0]; __syncthreads();

  float ev[8];
  float se = 0.f;
#pragma unroll
  for (int it = 0; it < 8; ++it) {
    int j = tid + it * 256;
    float e = 0.f;
    if (j < V_N) { e = expf(yv[it] - mx); se += e; }
    ev[it] = e;
  }
  sred[tid] = se; __syncthreads();
  for (int s = 128; s; s >>= 1) { if (tid < s) sred[tid] += sred[tid + s]; __syncthreads(); }
  se = sred[0]; __syncthreads();

  float part = 0.f;
#pragma unroll
  for (int it = 0; it < 8; ++it) {
    int j = tid + it * 256;
    if (j < V_N) part += X[base + j] * logf(ev[it] / se + 1e-10f);
  }
  sred[tid] = part; __syncthreads();
  for (int s = 128; s; s >>= 1) { if (tid < s) sred[tid] += sred[tid + s]; __syncthreads(); }
  if (tid == 0) atomicAdd(accp + z, -sred[0]);
}

// ---------------------------------------------------------------------------
// Row L2-normalize (BWE -> na/nb), 2-way
// ---------------------------------------------------------------------------
__global__ void rownorm2_kern(const float* __restrict__ X0, float* __restrict__ Y0,
                              const float* __restrict__ X1, float* __restrict__ Y1) {
  __shared__ float sred[256];
  const int z = blockIdx.z;
  const float* Xp = z ? X1 : X0;
  float* Yp = z ? Y1 : Y0;
  const int row = (int)blockIdx.x, tid = threadIdx.x;
  float s = 0.f;
  for (int j = tid; j < E_N; j += 256) { float v = Xp[(size_t)row * E_N + j]; s += v * v; }
  sred[tid] = s; __syncthreads();
  for (int st = 128; st; st >>= 1) { if (tid < st) sred[tid] += sred[tid + st]; __syncthreads(); }
  float sc = 1.f / fmaxf(sqrtf(sred[0]), 1e-12f);
  for (int j = tid; j < E_N; j += 256) Yp[(size_t)row * E_N + j] = Xp[(size_t)row * E_N + j] * sc;
}

// ---------------------------------------------------------------------------
// M = 1 - na @ nb^T ; writes K=exp(-10M) and K^T as bf16 (VP-strided).
// XCD-swizzled (grid 32x32 = 1024, divisible by 8).
// ---------------------------------------------------------------------------
__global__ __launch_bounds__(256) void gemm_nt_cost_kern(
    const float* __restrict__ NAp, const float* __restrict__ NBp,
    unsigned short* __restrict__ Kb, unsigned short* __restrict__ KTb) {
  __shared__ float As[16][68];
  __shared__ float Bs[16][68];
  int bx, by, bz;
  xcd_swizzle(bx, by, bz);
  const int tid = threadIdx.x;
  const int tx = tid & 15, ty = tid >> 4;
  const int row0 = by * 64, col0 = bx * 64;
  float acc[4][4];
#pragma unroll
  for (int i = 0; i < 4; ++i)
#pragma unroll
    for (int j = 0; j < 4; ++j) acc[i][j] = 0.f;

  for (int e0 = 0; e0 < E_N; e0 += 16) {
#pragma unroll
    for (int i = 0; i < 4; ++i) {
      int id = tid + 256 * i;
      int m = id >> 4, e = id & 15;
      int ge = e0 + e;
      int gr = row0 + m;
      As[e][m] = (gr < V_N && ge < E_N) ? NAp[(size_t)gr * E_N + ge] : 0.f;
      int gc = col0 + m;
      Bs[e][m] = (gc < V_N && ge < E_N) ? NBp[(size_t)gc * E_N + ge] : 0.f;
    }
    __syncthreads();
#pragma unroll
    for (int kk = 0; kk < 16; ++kk) {
      float4 av = *(const float4*)&As[kk][ty * 4];
      float4 bv = *(const float4*)&Bs[kk][tx * 4];
      float aa[4] = {av.x, av.y, av.z, av.w};
      float bb[4] = {bv.x, bv.y, bv.z, bv.w};
#pragma unroll
      for (int i = 0; i < 4; ++i)
#pragma unroll
        for (int j = 0; j < 4; ++j) acc[i][j] = fmaf(aa[i], bb[j], acc[i][j]);
    }
    __syncthreads();
  }
#pragma unroll
  for (int i = 0; i < 4; ++i) {
    int gi = row0 + ty * 4 + i;
    if (gi >= V_N) continue;
#pragma unroll
    for (int j = 0; j < 4; ++j) {
      int gj = col0 + tx * 4 + j;
      if (gj >= V_N) continue;
      float m = 1.f - acc[i][j];
      float kv = expf(-10.f * m);
      Kb[(size_t)gi * VP + gj] = f2bf(kv);
      KTb[(size_t)gj * VP + gi] = f2bf(kv);
    }
  }
}

// ---------------------------------------------------------------------------
// a/b marginals: softmax over vocab of phi row t (f32, VP-strided), 2-way
// ---------------------------------------------------------------------------
__global__ void topic_softmax2_kern(const float* __restrict__ p0, float* __restrict__ A0,
                                    const float* __restrict__ p1, float* __restrict__ A1) {
  __shared__ float sred[256];
  const int z = blockIdx.z;
  const float* phi = z ? p1 : p0;
  float* ATp = z ? A1 : A0;
  const int t = (int)blockIdx.x, tid = threadIdx.x;
  const size_t base = (size_t)t * V_N;
  float mx = -1e30f;
  for (int i = tid; i < V_N; i += 256) mx = fmaxf(mx, phi[base + i]);
  sred[tid] = mx; __syncthreads();
  for (int s = 128; s; s >>= 1) { if (tid < s) sred[tid] = fmaxf(sred[tid], sred[tid + s]); __syncthreads(); }
  mx = sred[0]; __syncthreads();
  float se = 0.f;
  for (int i = tid; i < V_N; i += 256) se += expf(phi[base + i] - mx);
  sred[tid] = se; __syncthreads();
  for (int s = 128; s; s >>= 1) { if (tid < s) sred[tid] += sred[tid + s]; __syncthreads(); }
  se = sred[0];
  for (int i = tid; i < V_N; i += 256) ATp[(size_t)t * VP + i] = expf(phi[base + i] - mx) / se;
}

// ---------------------------------------------------------------------------
// Rotation slots live in MFMA-B-FRAGMENT order (coalesced consumer loads).
// ---------------------------------------------------------------------------
__global__ void vinit_kern(unsigned short* __restrict__ VTp) {
  int id = (int)blockIdx.x * 256 + threadIdx.x;
  if (id >= SLOT_E) return;
  int e = id & 7, l = (id >> 3) & 63, ks = (id >> 9) & 15, t = (id >> 13) & 3, w = (id >> 15) & 3;
  int topic = t * 16 + (l & 15);
  int vocab = w * 512 + ks * 32 + (l >> 4) * 8 + e;
  VTp[id] = (topic < K_N && vocab < V_N) ? f2bf(1.0f / (float)V_N) : (unsigned short)0;
}

__global__ void finalize_kern(const float* __restrict__ accp, float* __restrict__ out) {
  if (threadIdx.x == 0)
    out[0] = (accp[0] + accp[1]) * (1.f / (float)B_N) + 0.1f * accp[2];
}

// ---------------------------------------------------------------------------
// Sinkhorn (R14/R17/R18 FROZEN): MLP sweep + distributed flags + per-wave
// group wait + bf16 fixed-point early exit (4-phase confirm, gated verdict).
// ---------------------------------------------------------------------------
__device__ __forceinline__ void sk_sweep(
    const bf16x8 (&Af)[16], const unsigned short* __restrict__ Xt,
    float* __restrict__ red, int wave, int lane) {
  const int m = lane & 15, q = lane >> 4;
  const unsigned short* xb = Xt + ((size_t)wave << 15) + lane * 8;
  bf16x8 Bv[4][16];
#pragma unroll
  for (int t = 0; t < 4; ++t)
#pragma unroll
    for (int ks = 0; ks < 16; ++ks)
      Bv[t][ks] = *(const bf16x8*)(xb + t * 8192 + ks * 512);
  __builtin_amdgcn_sched_barrier(0);
#pragma unroll
  for (int t = 0; t < 4; ++t) {
    f32x4n a = (f32x4n){0.f, 0.f, 0.f, 0.f};
#pragma unroll
    for (int ks = 0; ks < 16; ++ks)
      a = __builtin_amdgcn_mfma_f32_16x16x32_bf16(Af[ks], Bv[t][ks], a, 0, 0, 0);
    *(f32x4n*)&red[wave * 1280 + (t * 16 + m) * 20 + q * 4] = a;
  }
}

__device__ __forceinline__ void sk_sweep_km(
    const bf16x8 (&AfK)[16], const unsigned short* __restrict__ Xt,
    float* __restrict__ red, int wave, int lane) {
  const int m = lane & 15, q = lane >> 4;
  const unsigned short* xb = Xt + ((size_t)wave << 15) + lane * 8;
  bf16x8 Am[16];
#pragma unroll
  for (int ks = 0; ks < 16; ++ks) {
    union { bf16x8 v; unsigned short s[8]; } a, o;
    a.v = AfK[ks];
#pragma unroll
    for (int e = 0; e < 8; ++e) {
      float k = bf2f(a.s[e]);
      o.s[e] = (k > 0.f) ? f2bf(-0.1f * k * logf(k)) : (unsigned short)0;
    }
    Am[ks] = o.v;
  }
#pragma unroll
  for (int t = 0; t < 4; ++t) {
    f32x4n a = (f32x4n){0.f, 0.f, 0.f, 0.f};
#pragma unroll
    for (int ks = 0; ks < 16; ++ks) {
      bf16x8 bv = *(const bf16x8*)(xb + t * 8192 + ks * 512);
      a = __builtin_amdgcn_mfma_f32_16x16x32_bf16(Am[ks], bv, a, 0, 0, 0);
    }
    *(f32x4n*)&red[wave * 1280 + (t * 16 + m) * 20 + q * 4] = a;
  }
}

__global__ void __launch_bounds__(256, 1) sinkhorn_kern(
    const unsigned short* __restrict__ Kb, const unsigned short* __restrict__ KTb,
    const float* __restrict__ ATp, const float* __restrict__ BTp,
    unsigned short* __restrict__ ROTp, float* __restrict__ accp,
    int* __restrict__ flags) {
  __shared__ float red[5120];
  __shared__ int chgLDS[4];
  __shared__ int frzLDS[4];
  const int wg = (int)blockIdx.x, tid = threadIdx.x;
  const int wave = tid >> 6, lane = tid & 63;
  const int m = lane & 15, q = lane >> 4;

  bf16x8 AfK[16], AfT[16];
  {
    const unsigned short* arowK = Kb  + (size_t)(wg * 16 + m) * VP + wave * 512 + q * 8;
    const unsigned short* arowT = KTb + (size_t)(wg * 16 + m) * VP + wave * 512 + q * 8;
#pragma unroll
    for (int ks = 0; ks < 16; ++ks) {
      AfK[ks] = *(const bf16x8*)(arowK + ks * 32);
      AfT[ks] = *(const bf16x8*)(arowT + ks * 32);
    }
  }
  const int c = tid >> 2, r0 = (tid & 3) * 4;
  const f32x4n aA = *(const f32x4n*)(ATp + (size_t)c * VP + wg * 16 + r0);
  const f32x4n aB = *(const f32x4n*)(BTp + (size_t)c * VP + wg * 16 + r0);
  const int out_off = (((wg >> 5) * 4 + (c >> 4)) * 16 + ((wg & 31) >> 1)) * 512
                    + ((((wg & 1) << 1) | (r0 >> 3)) * 16 + (c & 15)) * 8 + (r0 & 7);

  int cnt8 = 0, sprev = 0;
  ushort4 pE = {0, 0, 0, 0}, pO = {0, 0, 0, 0};
  int lastph = 2 * SK_ITER - 1;

  for (int ph = 0; ph < 2 * SK_ITER; ++ph) {
    if (ph && (ph & 3) == 0) {
      __syncthreads();
      if (frzLDS[0] && frzLDS[1] && frzLDS[2] && frzLDS[3]) { lastph = ph - 1; break; }
    }
    const unsigned short* src = ROTp + (size_t)((ph + 31) & 31) * SLOT_E;
    unsigned short* dst = ROTp + (size_t)(ph & 31) * SLOT_E;
    if ((ph & 1) == 0) sk_sweep(AfK, src, red, wave, lane);
    else               sk_sweep(AfT, src, red, wave, lane);
    __syncthreads();
    {
      f32x4n s = (f32x4n){0.f, 0.f, 0.f, 0.f};
#pragma unroll
      for (int w = 0; w < 4; ++w) s += *(const f32x4n*)&red[w * 1280 + c * 20 + r0];
      f32x4n a4 = ((ph & 1) == 0) ? aA : aB;
      f32x4n u = a4 / (s + 1e-16f);
      ushort4 ub;
      ub.x = f2bf(u.x); ub.y = f2bf(u.y); ub.z = f2bf(u.z); ub.w = f2bf(u.w);
      ushort4 pv = (ph & 1) ? pO : pE;
      int changed = (ph < 2) ? 1 :
          ((((ub.x ^ pv.x) | (ub.y ^ pv.y)) | ((ub.z ^ pv.z) | (ub.w ^ pv.w))) != 0);
      if (ph & 1) pO = ub; else pE = ub;
      unsigned long long cb = __ballot(changed);
      if (lane == 0) chgLDS[wave] = (cb != 0ull) ? 1 : 0;
      coh_store8(dst + out_off, ub);
    }
    __syncthreads();
    if (tid == 0) {
      int changed_wg = chgLDS[0] | chgLDS[1] | chgLDS[2] | chgLDS[3];
      cnt8 = changed_wg ? 0 : (cnt8 + 1);
      int scur = (cnt8 >= 4) ? 1 : 0;
      __hip_atomic_store(&flags[wg * 32], ((ph + 1) << 2) | (scur << 1) | sprev,
                         __ATOMIC_RELAXED, __HIP_MEMORY_SCOPE_AGENT);
      sprev = scur;
    }
    {
      const int epoch = ph + 1;
      const int idx = (wave * 32 + (lane & 31)) * 32;
      int v = epoch << 2;
      int spin = 0;
      for (;;) {
        if (lane < 32)
          v = __hip_atomic_load(&flags[idx], __ATOMIC_RELAXED, __HIP_MEMORY_SCOPE_AGENT);
        if (__ballot((v >> 2) >= epoch) == ~0ull) break;
        __builtin_amdgcn_s_sleep(1);
        if (++spin >= (1 << 17)) break;
      }
      if ((epoch & 3) == 0) {   // verdict consumed only at next %4 break-check
        int frz = (lane < 32)
          ? (((v >> 2) == epoch) ? ((v >> 1) & 1) : (v & 1))
          : 1;
        unsigned long long fb = __ballot(frz != 0);
        if (lane == 0) frzLDS[wave] = (fb == ~0ull) ? 1 : 0;
      }
    }
  }

  const int lodd = (lastph & 1) ? lastph : (lastph - 1);
  const unsigned short* vfin = ROTp + (size_t)(lodd & 31) * SLOT_E;
  float u4[4];

  sk_sweep(AfK, vfin, red, wave, lane);
  __syncthreads();
  {
    f32x4n s = (f32x4n){0.f, 0.f, 0.f, 0.f};
#pragma unroll
    for (int w = 0; w < 4; ++w) s += *(const f32x4n*)&red[w * 1280 + c * 20 + r0];
#pragma unroll
    for (int i = 0; i < 4; ++i) u4[i] = aA[i] / (s[i] + 1e-16f);
  }
  __syncthreads();
  sk_sweep_km(AfK, vfin, red, wave, lane);
  __syncthreads();
  float part = 0.f;
  {
    f32x4n s = (f32x4n){0.f, 0.f, 0.f, 0.f};
#pragma unroll
    for (int w = 0; w < 4; ++w) s += *(const f32x4n*)&red[w * 1280 + c * 20 + r0];
#pragma unroll
    for (int i = 0; i < 4; ++i) part += u4[i] * s[i];
  }
  __syncthreads();
  red[tid] = part; __syncthreads();
  for (int st = 128; st; st >>= 1) { if (tid < st) red[tid] += red[tid + st]; __syncthreads(); }
  if (tid == 0) atomicAdd(accp + 2, red[0]);
}

// ---------------------------------------------------------------------------
extern "C" void kernel_launch(void* const* d_in, const int* in_sizes, int n_in,
                              void* d_out, int out_size, void* d_ws, size_t ws_size,
                              hipStream_t stream) {
  const float* x_a   = (const float*)d_in[0];
  const float* x_b   = (const float*)d_in[1];
  const float* eps_a = (const float*)d_in[2];
  const float* eps_b = (const float*)d_in[3];
  const float* W1_a  = (const float*)d_in[4];
  const float* b1_a  = (const float*)d_in[5];
  const float* W2_a  = (const float*)d_in[6];
  const float* b2_a  = (const float*)d_in[7];
  const float* Wmu_a = (const float*)d_in[8];
  const float* bmu_a = (const float*)d_in[9];
  const float* Wlv_a = (const float*)d_in[10];
  const float* blv_a = (const float*)d_in[11];
  const float* mbn_a = (const float*)d_in[12];
  const float* lbn_a = (const float*)d_in[13];
  const float* W1_b  = (const float*)d_in[14];
  const float* b1_b  = (const float*)d_in[15];
  const float* W2_b  = (const float*)d_in[16];
  const float* b2_b  = (const float*)d_in[17];
  const float* Wmu_b = (const float*)d_in[18];
  const float* bmu_b = (const float*)d_in[19];
  const float* Wlv_b = (const float*)d_in[20];
  const float* blv_b = (const float*)d_in[21];
  const float* mbn_b = (const float*)d_in[22];
  const float* lbn_b = (const float*)d_in[23];
  const float* dbn_a = (const float*)d_in[24];
  const float* dbn_b = (const float*)d_in[25];
  const float* phi_a = (const float*)d_in[26];
  const float* phi_b = (const float*)d_in[27];
  const float* bwe_a = (const float*)d_in[28];
  const float* bwe_b = (const float*)d_in[29];
  float* out = (float*)d_out;

  // ---- fused workspace layout (~37.9 MB; DEC overlays H1/H2) ----
  char* ws = (char*)d_ws;
  const size_t OFF_ACC  = 0;                      // 256 B
  const size_t OFF_BAR  = 256;                    // flags: 128 lines x 128 B
  const size_t OFF_ST   = OFF_BAR + 16384;        // stats block (196608 B)
  const size_t ST_SUM4  = OFF_ST;
  const size_t ST_SQ4   = ST_SUM4 + 32768;
  const size_t ST_MEAN4 = ST_SQ4 + 32768;
  const size_t ST_RSTD4 = ST_MEAN4 + 32768;
  const size_t ST_DSUM2 = ST_RSTD4 + 32768;
  const size_t ST_DSQ2  = ST_DSUM2 + 16384;
  const size_t ST_DMEAN2= ST_DSQ2 + 16384;
  const size_t ST_DRSTD2= ST_DMEAN2 + 16384;
  const size_t OFF_TH   = OFF_ST + 196608;
  const size_t OFF_MU   = OFF_TH + 1638400;
  const size_t OFF_LV   = OFF_MU + 1638400;
  const size_t OFF_BIG  = OFF_LV + 1638400;
  const size_t NEED     = OFF_BIG + 32768000;     // ~37.9 MB
  if (ws_size < NEED) return;

  float* ACCp = (float*)(ws + OFF_ACC);
  int*   FLGp = (int*)(ws + OFF_BAR);
  float* SUM4 = (float*)(ws + ST_SUM4);
  float* SQ4  = (float*)(ws + ST_SQ4);
  float* MEAN4= (float*)(ws + ST_MEAN4);
  float* RSTD4= (float*)(ws + ST_RSTD4);
  float* DSUM2= (float*)(ws + ST_DSUM2);
  float* DSQ2 = (float*)(ws + ST_DSQ2);
  float* DMEAN2=(float*)(ws + ST_DMEAN2);
  float* DRSTD2=(float*)(ws + ST_DRSTD2);
  float* THa  = (float*)(ws + OFF_TH);
  float* THb  = THa + 204800;
  float* MUa  = (float*)(ws + OFF_MU);
  float* MUb  = MUa + 204800;
  float* LVa  = (float*)(ws + OFF_LV);
  float* LVb  = LVa + 204800;
  float* H1a  = (float*)(ws + OFF_BIG);
  float* H1b  = H1a + 2048000;
  float* H2a  = H1b + 2048000;
  float* H2b  = H2a + 2048000;
  unsigned short* DECa = (unsigned short*)(ws + OFF_BIG);
  unsigned short* DECb = DECa + 8192000;
  // phase-2 overlay (KB|KT contiguous; AT|BT contiguous)
  float* NAp  = (float*)(ws + OFF_BIG);
  float* NBp  = (float*)(ws + OFF_BIG + 2400000);
  unsigned short* KBp = (unsigned short*)(ws + OFF_BIG + 4800000);
  unsigned short* KTp = (unsigned short*)(ws + OFF_BIG + 13188608);
  float* ATp  = (float*)(ws + OFF_BIG + 21577216);
  float* BTp  = (float*)(ws + OFF_BIG + 22101504);
  unsigned short* ROTp = (unsigned short*)(ws + OFF_BIG + 22625792);
  unsigned short* SLOT31 = ROTp + (size_t)31 * SLOT_E;

  hipMemsetAsync(ACCp, 0, 256, stream);
  hipMemsetAsync(FLGp, 0, 16384, stream);
  hipMemsetAsync((void*)(ws + OFF_ST), 0, 196608, stream);

  // ---- phase 1: both encoders fused via blockIdx.z (BK=32 tiles, swizzled) ----
  gemm_nn2_kern<<<dim3(8, 64, 2), 256, 0, stream>>>(
      x_a, W1_a, b1_a, H1a, x_b, W1_b, b1_b, H1b, B_N, H_N, V_N, 1, 0);
  gemm_nn2_kern<<<dim3(8, 64, 2), 256, 0, stream>>>(
      H1a, W2_a, b2_a, H2a, H1b, W2_b, b2_b, H2b, B_N, H_N, H_N, 1, 0);
  gemm_nn4_kern<<<dim3(1, 64, 4), 256, 0, stream>>>(
      H2a, Wmu_a, bmu_a, MUa,  H2a, Wlv_a, blv_a, LVa,
      H2b, Wmu_b, bmu_b, MUb,  H2b, Wlv_b, blv_b, LVb,
      B_N, K_N, H_N, 0, 0);
  colstats4_kern<<<dim3(1, 16, 4), 256, 0, stream>>>(MUa, LVa, MUb, LVb, K_N, 256, SUM4, SQ4);
  finstats_kern<<<32, 256, 0, stream>>>(SUM4, SQ4, 8192, 1.f / B_N, MEAN4, RSTD4);
  reparam2_kern<<<dim3(B_N / 4, 1, 2), 256, 0, stream>>>(
      MUa, LVa, MUb, LVb, MEAN4, RSTD4,
      mbn_a, lbn_a, mbn_b, lbn_b, eps_a, eps_b, THa, THb, ACCp);
  gemm_nn2_kern<<<dim3(32, 64, 2), 256, 0, stream>>>(
      THa, phi_a, nullptr, DECa, THb, phi_b, nullptr, DECb, B_N, V_N, K_N, 0, 1);
  colstats_bf2_kern<<<dim3(8, 16, 2), 256, 0, stream>>>(DECa, DECb, V_N, 256, DSUM2, DSQ2);
  finstats_kern<<<16, 256, 0, stream>>>(DSUM2, DSQ2, 4096, 1.f / B_N, DMEAN2, DRSTD2);
  decode_rec2_kern<<<dim3(B_N, 1, 2), 256, 0, stream>>>(
      DECa, DECb, DMEAN2, DRSTD2, dbn_a, dbn_b, x_a, x_b, ACCp);

  // ---- phase 2: Sinkhorn prep (overlays BIG; merged memsets) ----
  hipMemsetAsync(KBp, 0, 2 * (size_t)VP * VP * 2, stream);   // KB + KT (contiguous)
  hipMemsetAsync(ATp, 0, 2 * (size_t)TP * VP * 4, stream);   // AT + BT (contiguous)

  rownorm2_kern<<<dim3(V_N, 1, 2), 256, 0, stream>>>(bwe_a, NAp, bwe_b, NBp);
  gemm_nt_cost_kern<<<dim3(32, 32), 256, 0, stream>>>(NAp, NBp, KBp, KTp);
  topic_softmax2_kern<<<dim3(K_N, 1, 2), 256, 0, stream>>>(phi_a, ATp, phi_b, BTp);
  vinit_kern<<<SLOT_E / 256, 256, 0, stream>>>(SLOT31);

  // ---- Sinkhorn main loop (early exit, 4-phase confirm) ----
  sinkhorn_kern<<<dim3(SK_NWG), dim3(256), 0, stream>>>(KBp, KTp, ATp, BTp,
                                                        ROTp, ACCp, FLGp);

  finalize_kern<<<1, 64, 0, stream>>>(ACCp, out);
  (void)in_sizes; (void)n_in; (void)out_size;
}

// Round 13
// 1728.599 us; speedup vs baseline: 1.1344x; 1.1344x over previous
//
#include <hip/hip_runtime.h>

// Problem dims
#define B_N 4096
#define V_N 2000
#define K_N 50
#define H_N 500
#define E_N 300
#define VP  2048   // padded vocab (mult of 32 for MFMA k)
#define TP  64     // padded topics
#define SK_NWG 128
#define SK_ITER 500
#define SLOT_E (TP * VP)   // ushort elements per rotation slot (256 KB)

typedef short bf16x8 __attribute__((ext_vector_type(8)));
typedef float f32x4n __attribute__((ext_vector_type(4)));

__device__ __forceinline__ unsigned short f2bf(float f) {
  unsigned int x = __float_as_uint(f);
  x = (x + 0x7FFFu + ((x >> 16) & 1u)) >> 16;
  return (unsigned short)x;
}
__device__ __forceinline__ float bf2f(unsigned short h) {
  return __uint_as_float((unsigned int)h << 16);
}
__device__ __forceinline__ float softplusf(float x) {
  return fmaxf(x, 0.f) + log1pf(expf(-fabsf(x)));
}

// Agent-coherent 8B store (write-through to the coherence point).
__device__ __forceinline__ void coh_store8(unsigned short* p, ushort4 val) {
  union { ushort4 s; unsigned long long u; } cvt; cvt.s = val;
  __hip_atomic_store((unsigned long long*)p, cvt.u,
                     __ATOMIC_RELAXED, __HIP_MEMORY_SCOPE_AGENT);
}

// R18: bijective chunked XCD swizzle (kept; small but positive).
// R19 (BK=32) REVERTED: it regressed 1.738 -> 1.961 ms (VGPR/occupancy loss).
// The 64-tile/BK=16/4-WG-per-CU GEMM is a measured local optimum (R16, R19).
__device__ __forceinline__ void xcd_swizzle(int& bx, int& by, int& bz) {
  const int gx = (int)gridDim.x, gy = (int)gridDim.y;
  const int NB = gx * gy * (int)gridDim.z;
  const int lin = (int)blockIdx.x + gx * ((int)blockIdx.y + gy * (int)blockIdx.z);
  const int chunk = NB >> 3;
  const int lp = (lin & 7) * chunk + (lin >> 3);
  bx = lp % gx;
  const int tmp = lp / gx;
  by = tmp % gy;
  bz = tmp / gy;
}

// ---------------------------------------------------------------------------
// 64-tile fp32 GEMM body (R15/R18). LDS dbuf + register prefetch +
// sched_barrier; 1 barrier/iter; bit-identical k-order.
// ---------------------------------------------------------------------------
__device__ __forceinline__ void gemm_tile_body(
    const float* __restrict__ A, const float* __restrict__ Bm,
    const float* __restrict__ bias, void* __restrict__ Cv,
    int M, int N, int Kd, int act, int bf16out, int bx, int by,
    float (*As)[16][68], float (*Bs)[16][68]) {
  const int tid = threadIdx.x;
  const int tx = tid & 15, ty = tid >> 4;
  const int row0 = by * 64, col0 = bx * 64;
  float acc[4][4];
#pragma unroll
  for (int i = 0; i < 4; ++i)
#pragma unroll
    for (int j = 0; j < 4; ++j) acc[i][j] = 0.f;

  float pa[4], pb[4];
#pragma unroll
  for (int i = 0; i < 4; ++i) {
    int id = tid + 256 * i;
    int m = id >> 4, kk = id & 15;
    int gr = row0 + m;
    pa[i] = (gr < M && kk < Kd) ? A[(size_t)gr * Kd + kk] : 0.f;
  }
#pragma unroll
  for (int i = 0; i < 4; ++i) {
    int id = tid + 256 * i;
    int kk = id >> 6, n = id & 63;
    int gc = col0 + n;
    pb[i] = (kk < Kd && gc < N) ? Bm[(size_t)kk * N + gc] : 0.f;
  }
#pragma unroll
  for (int i = 0; i < 4; ++i) { int id = tid + 256 * i; As[0][id & 15][id >> 4] = pa[i]; }
#pragma unroll
  for (int i = 0; i < 4; ++i) { int id = tid + 256 * i; Bs[0][id >> 6][id & 63] = pb[i]; }
  __syncthreads();

  const int nt = (Kd + 15) >> 4;
  for (int t = 1; t < nt; ++t) {
    const int k0 = t << 4;
#pragma unroll
    for (int i = 0; i < 4; ++i) {
      int id = tid + 256 * i;
      int m = id >> 4, kk = id & 15;
      int gr = row0 + m, gk = k0 + kk;
      pa[i] = (gr < M && gk < Kd) ? A[(size_t)gr * Kd + gk] : 0.f;
    }
#pragma unroll
    for (int i = 0; i < 4; ++i) {
      int id = tid + 256 * i;
      int kk = id >> 6, n = id & 63;
      int gk = k0 + kk, gc = col0 + n;
      pb[i] = (gk < Kd && gc < N) ? Bm[(size_t)gk * N + gc] : 0.f;
    }
    __builtin_amdgcn_sched_barrier(0);
    const int cb = (t - 1) & 1;
#pragma unroll
    for (int kk = 0; kk < 16; ++kk) {
      float4 av = *(const float4*)&As[cb][kk][ty * 4];
      float4 bv = *(const float4*)&Bs[cb][kk][tx * 4];
      float aa[4] = {av.x, av.y, av.z, av.w};
      float bb[4] = {bv.x, bv.y, bv.z, bv.w};
#pragma unroll
      for (int i = 0; i < 4; ++i)
#pragma unroll
        for (int j = 0; j < 4; ++j) acc[i][j] = fmaf(aa[i], bb[j], acc[i][j]);
    }
    const int wb = t & 1;
#pragma unroll
    for (int i = 0; i < 4; ++i) { int id = tid + 256 * i; As[wb][id & 15][id >> 4] = pa[i]; }
#pragma unroll
    for (int i = 0; i < 4; ++i) { int id = tid + 256 * i; Bs[wb][id >> 6][id & 63] = pb[i]; }
    __syncthreads();
  }
  const int lb = (nt - 1) & 1;
#pragma unroll
  for (int kk = 0; kk < 16; ++kk) {
    float4 av = *(const float4*)&As[lb][kk][ty * 4];
    float4 bv = *(const float4*)&Bs[lb][kk][tx * 4];
    float aa[4] = {av.x, av.y, av.z, av.w};
    float bb[4] = {bv.x, bv.y, bv.z, bv.w};
#pragma unroll
    for (int i = 0; i < 4; ++i)
#pragma unroll
      for (int j = 0; j < 4; ++j) acc[i][j] = fmaf(aa[i], bb[j], acc[i][j]);
  }
#pragma unroll
  for (int i = 0; i < 4; ++i) {
    int row = row0 + ty * 4 + i;
    if (row >= M) continue;
#pragma unroll
    for (int j = 0; j < 4; ++j) {
      int col = col0 + tx * 4 + j;
      if (col >= N) continue;
      float v = acc[i][j] + (bias ? bias[col] : 0.f);
      if (act) v = softplusf(v);
      if (bf16out) ((unsigned short*)Cv)[(size_t)row * N + col] = f2bf(v);
      else         ((float*)Cv)[(size_t)row * N + col] = v;
    }
  }
}

// 2-way (z picks side a/b), XCD-swizzled
__global__ __launch_bounds__(256) void gemm_nn2_kern(
    const float* A0, const float* B0, const float* b0, void* C0,
    const float* A1, const float* B1, const float* b1, void* C1,
    int M, int N, int Kd, int act, int bf16out) {
  __shared__ float As[2][16][68];
  __shared__ float Bs[2][16][68];
  int bx, by, bz;
  xcd_swizzle(bx, by, bz);
  gemm_tile_body(bz ? A1 : A0, bz ? B1 : B0, bz ? b1 : b0, bz ? C1 : C0,
                 M, N, Kd, act, bf16out, bx, by, As, Bs);
}

// 4-way (mu_a, lv_a, mu_b, lv_b), XCD-swizzled
__global__ __launch_bounds__(256) void gemm_nn4_kern(
    const float* A0, const float* B0, const float* b0, void* C0,
    const float* A1, const float* B1, const float* b1, void* C1,
    const float* A2, const float* B2, const float* b2, void* C2,
    const float* A3, const float* B3, const float* b3, void* C3,
    int M, int N, int Kd, int act, int bf16out) {
  __shared__ float As[2][16][68];
  __shared__ float Bs[2][16][68];
  int bx, by, bz;
  xcd_swizzle(bx, by, bz);
  const float* A = (bz == 0) ? A0 : (bz == 1) ? A1 : (bz == 2) ? A2 : A3;
  const float* B = (bz == 0) ? B0 : (bz == 1) ? B1 : (bz == 2) ? B2 : B3;
  const float* bb = (bz == 0) ? b0 : (bz == 1) ? b1 : (bz == 2) ? b2 : b3;
  void* C = (bz == 0) ? C0 : (bz == 1) ? C1 : (bz == 2) ? C2 : C3;
  gemm_tile_body(A, B, bb, C, M, N, Kd, act, bf16out, bx, by, As, Bs);
}

// ---------------------------------------------------------------------------
// Column partial sums (BN stats) -- 4-way / 2-way fused
// ---------------------------------------------------------------------------
__global__ void colstats4_kern(
    const float* X0, const float* X1, const float* X2, const float* X3,
    int C, int rowsPer, float* __restrict__ sums, float* __restrict__ sumsq) {
  const int z = blockIdx.z;
  const float* X = (z == 0) ? X0 : (z == 1) ? X1 : (z == 2) ? X2 : X3;
  float* s_ = sums + (size_t)z * 2048;
  float* q_ = sumsq + (size_t)z * 2048;
  int c = (int)blockIdx.x * 256 + threadIdx.x;
  if (c >= C) return;
  int r0 = (int)blockIdx.y * rowsPer;
  float s = 0.f, s2 = 0.f;
  for (int r = r0; r < r0 + rowsPer; ++r) {
    float v = X[(size_t)r * C + c];
    s += v; s2 += v * v;
  }
  atomicAdd(&s_[c], s);
  atomicAdd(&q_[c], s2);
}

__global__ void colstats_bf2_kern(
    const unsigned short* X0, const unsigned short* X1,
    int C, int rowsPer, float* __restrict__ sums, float* __restrict__ sumsq) {
  const int z = blockIdx.z;
  const unsigned short* X = z ? X1 : X0;
  float* s_ = sums + (size_t)z * 2048;
  float* q_ = sumsq + (size_t)z * 2048;
  int c = (int)blockIdx.x * 256 + threadIdx.x;
  if (c >= C) return;
  int r0 = (int)blockIdx.y * rowsPer;
  float s = 0.f, s2 = 0.f;
  for (int r = r0; r < r0 + rowsPer; ++r) {
    float v = bf2f(X[(size_t)r * C + c]);
    s += v; s2 += v * v;
  }
  atomicAdd(&s_[c], s);
  atomicAdd(&q_[c], s2);
}

__global__ void finstats_kern(const float* __restrict__ sums, const float* __restrict__ sumsq,
                              int C, float invM, float* __restrict__ mean,
                              float* __restrict__ rstd) {
  int c = (int)blockIdx.x * 256 + threadIdx.x;
  if (c >= C) return;
  float mu = sums[c] * invM;
  float var = sumsq[c] * invM - mu * mu;
  mean[c] = mu;
  rstd[c] = rsqrtf(var + 1e-5f);
}

// ---------------------------------------------------------------------------
// BN-apply + reparam + row-softmax(50) -> theta ; accumulate KLD (2-way)
// ---------------------------------------------------------------------------
__global__ __launch_bounds__(256) void reparam2_kern(
    const float* __restrict__ MU0, const float* __restrict__ LV0,
    const float* __restrict__ MU1, const float* __restrict__ LV1,
    const float* __restrict__ mean4, const float* __restrict__ rstd4,
    const float* __restrict__ mbn0, const float* __restrict__ lbn0,
    const float* __restrict__ mbn1, const float* __restrict__ lbn1,
    const float* __restrict__ eps0, const float* __restrict__ eps1,
    float* __restrict__ TH0, float* __restrict__ TH1,
    float* __restrict__ accp) {
  const int z = blockIdx.z;
  const float* MUp = z ? MU1 : MU0;
  const float* LVp = z ? LV1 : LV0;
  const float* mmean = mean4 + (size_t)(z * 2) * 2048;
  const float* mrstd = rstd4 + (size_t)(z * 2) * 2048;
  const float* lmean = mean4 + (size_t)(z * 2 + 1) * 2048;
  const float* lrstd = rstd4 + (size_t)(z * 2 + 1) * 2048;
  const float* mbn = z ? mbn1 : mbn0;
  const float* lbn = z ? lbn1 : lbn0;
  const float* epsb = z ? eps1 : eps0;
  float* TH = z ? TH1 : TH0;

  const int wave = threadIdx.x >> 6, lane = threadIdx.x & 63;
  const int row = (int)blockIdx.x * 4 + wave;
  const bool act = lane < K_N;
  float mu = 0.f, lv = 0.f, zz = 0.f;
  size_t base = (size_t)row * K_N + lane;
  if (act) {
    mu = (MUp[base] - mmean[lane]) * mrstd[lane] + mbn[lane];
    lv = (LVp[base] - lmean[lane]) * lrstd[lane] + lbn[lane];
    zz = mu + expf(0.5f * lv) * epsb[base];
  }
  float zm = act ? zz : -1e30f;
#pragma unroll
  for (int m = 32; m; m >>= 1) zm = fmaxf(zm, __shfl_xor(zm, m));
  float e = act ? expf(zz - zm) : 0.f;
  float se = e;
#pragma unroll
  for (int m = 32; m; m >>= 1) se += __shfl_xor(se, m);
  if (act) TH[base] = e / se;
  float kt = 0.f;
  if (act) {
    float var = expf(lv);
    kt = var * (1.f / 0.98f) + mu * mu * (1.f / 0.98f) + logf(0.98f) - lv;
  }
  float sk = kt;
#pragma unroll
  for (int m = 32; m; m >>= 1) sk += __shfl_xor(sk, m);
  if (lane == 0) atomicAdd(accp + z, 0.5f * (sk - (float)K_N));
}

// ---------------------------------------------------------------------------
// decode: BN-apply + row softmax + rec; one block/row (2-way), single pass.
// ---------------------------------------------------------------------------
__global__ __launch_bounds__(256) void decode_rec2_kern(
    const unsigned short* __restrict__ D0, const unsigned short* __restrict__ D1,
    const float* __restrict__ mean2, const float* __restrict__ rstd2,
    const float* __restrict__ bias0, const float* __restrict__ bias1,
    const float* __restrict__ X0, const float* __restrict__ X1,
    float* __restrict__ accp) {
  __shared__ float sred[256];
  const int z = blockIdx.z;
  const unsigned short* DECb = z ? D1 : D0;
  const float* mean = mean2 + (size_t)z * 2048;
  const float* rstd = rstd2 + (size_t)z * 2048;
  const float* bias = z ? bias1 : bias0;
  const float* X = z ? X1 : X0;
  const int row = (int)blockIdx.x, tid = threadIdx.x;
  const size_t base = (size_t)row * V_N;

  float yv[8];
  float mx = -1e30f;
#pragma unroll
  for (int it = 0; it < 8; ++it) {
    int j = tid + it * 256;
    float y = -1e30f;
    if (j < V_N) y = (bf2f(DECb[base + j]) - mean[j]) * rstd[j] + bias[j];
    yv[it] = y;
    mx = fmaxf(mx, y);
  }
  sred[tid] = mx; __syncthreads();
  for (int s = 128; s; s >>= 1) { if (tid < s) sred[tid] = fmaxf(sred[tid], sred[tid + s]); __syncthreads(); }
  mx = sred[0]; __syncthreads();

  float ev[8];
  float se = 0.f;
#pragma unroll
  for (int it = 0; it < 8; ++it) {
    int j = tid + it * 256;
    float e = 0.f;
    if (j < V_N) { e = expf(yv[it] - mx); se += e; }
    ev[it] = e;
  }
  sred[tid] = se; __syncthreads();
  for (int s = 128; s; s >>= 1) { if (tid < s) sred[tid] += sred[tid + s]; __syncthreads(); }
  se = sred[0]; __syncthreads();

  float part = 0.f;
#pragma unroll
  for (int it = 0; it < 8; ++it) {
    int j = tid + it * 256;
    if (j < V_N) part += X[base + j] * logf(ev[it] / se + 1e-10f);
  }
  sred[tid] = part; __syncthreads();
  for (int s = 128; s; s >>= 1) { if (tid < s) sred[tid] += sred[tid + s]; __syncthreads(); }
  if (tid == 0) atomicAdd(accp + z, -sred[0]);
}

// ---------------------------------------------------------------------------
// Row L2-normalize (BWE -> na/nb), 2-way
// ---------------------------------------------------------------------------
__global__ void rownorm2_kern(const float* __restrict__ X0, float* __restrict__ Y0,
                              const float* __restrict__ X1, float* __restrict__ Y1) {
  __shared__ float sred[256];
  const int z = blockIdx.z;
  const float* Xp = z ? X1 : X0;
  float* Yp = z ? Y1 : Y0;
  const int row = (int)blockIdx.x, tid = threadIdx.x;
  float s = 0.f;
  for (int j = tid; j < E_N; j += 256) { float v = Xp[(size_t)row * E_N + j]; s += v * v; }
  sred[tid] = s; __syncthreads();
  for (int st = 128; st; st >>= 1) { if (tid < st) sred[tid] += sred[tid + st]; __syncthreads(); }
  float sc = 1.f / fmaxf(sqrtf(sred[0]), 1e-12f);
  for (int j = tid; j < E_N; j += 256) Yp[(size_t)row * E_N + j] = Xp[(size_t)row * E_N + j] * sc;
}

// ---------------------------------------------------------------------------
// M = 1 - na @ nb^T ; writes K=exp(-10M) and K^T as bf16 (VP-strided).
// XCD-swizzled (grid 32x32 = 1024, divisible by 8).
// ---------------------------------------------------------------------------
__global__ __launch_bounds__(256) void gemm_nt_cost_kern(
    const float* __restrict__ NAp, const float* __restrict__ NBp,
    unsigned short* __restrict__ Kb, unsigned short* __restrict__ KTb) {
  __shared__ float As[16][68];
  __shared__ float Bs[16][68];
  int bx, by, bz;
  xcd_swizzle(bx, by, bz);
  const int tid = threadIdx.x;
  const int tx = tid & 15, ty = tid >> 4;
  const int row0 = by * 64, col0 = bx * 64;
  float acc[4][4];
#pragma unroll
  for (int i = 0; i < 4; ++i)
#pragma unroll
    for (int j = 0; j < 4; ++j) acc[i][j] = 0.f;

  for (int e0 = 0; e0 < E_N; e0 += 16) {
#pragma unroll
    for (int i = 0; i < 4; ++i) {
      int id = tid + 256 * i;
      int m = id >> 4, e = id & 15;
      int ge = e0 + e;
      int gr = row0 + m;
      As[e][m] = (gr < V_N && ge < E_N) ? NAp[(size_t)gr * E_N + ge] : 0.f;
      int gc = col0 + m;
      Bs[e][m] = (gc < V_N && ge < E_N) ? NBp[(size_t)gc * E_N + ge] : 0.f;
    }
    __syncthreads();
#pragma unroll
    for (int kk = 0; kk < 16; ++kk) {
      float4 av = *(const float4*)&As[kk][ty * 4];
      float4 bv = *(const float4*)&Bs[kk][tx * 4];
      float aa[4] = {av.x, av.y, av.z, av.w};
      float bb[4] = {bv.x, bv.y, bv.z, bv.w};
#pragma unroll
      for (int i = 0; i < 4; ++i)
#pragma unroll
        for (int j = 0; j < 4; ++j) acc[i][j] = fmaf(aa[i], bb[j], acc[i][j]);
    }
    __syncthreads();
  }
#pragma unroll
  for (int i = 0; i < 4; ++i) {
    int gi = row0 + ty * 4 + i;
    if (gi >= V_N) continue;
#pragma unroll
    for (int j = 0; j < 4; ++j) {
      int gj = col0 + tx * 4 + j;
      if (gj >= V_N) continue;
      float m = 1.f - acc[i][j];
      float kv = expf(-10.f * m);
      Kb[(size_t)gi * VP + gj] = f2bf(kv);
      KTb[(size_t)gj * VP + gi] = f2bf(kv);
    }
  }
}

// ---------------------------------------------------------------------------
// a/b marginals: softmax over vocab of phi row t (f32, VP-strided), 2-way
// ---------------------------------------------------------------------------
__global__ void topic_softmax2_kern(const float* __restrict__ p0, float* __restrict__ A0,
                                    const float* __restrict__ p1, float* __restrict__ A1) {
  __shared__ float sred[256];
  const int z = blockIdx.z;
  const float* phi = z ? p1 : p0;
  float* ATp = z ? A1 : A0;
  const int t = (int)blockIdx.x, tid = threadIdx.x;
  const size_t base = (size_t)t * V_N;
  float mx = -1e30f;
  for (int i = tid; i < V_N; i += 256) mx = fmaxf(mx, phi[base + i]);
  sred[tid] = mx; __syncthreads();
  for (int s = 128; s; s >>= 1) { if (tid < s) sred[tid] = fmaxf(sred[tid], sred[tid + s]); __syncthreads(); }
  mx = sred[0]; __syncthreads();
  float se = 0.f;
  for (int i = tid; i < V_N; i += 256) se += expf(phi[base + i] - mx);
  sred[tid] = se; __syncthreads();
  for (int s = 128; s; s >>= 1) { if (tid < s) sred[tid] += sred[tid + s]; __syncthreads(); }
  se = sred[0];
  for (int i = tid; i < V_N; i += 256) ATp[(size_t)t * VP + i] = expf(phi[base + i] - mx) / se;
}

// ---------------------------------------------------------------------------
// Rotation slots live in MFMA-B-FRAGMENT order (coalesced consumer loads).
// ---------------------------------------------------------------------------
__global__ void vinit_kern(unsigned short* __restrict__ VTp) {
  int id = (int)blockIdx.x * 256 + threadIdx.x;
  if (id >= SLOT_E) return;
  int e = id & 7, l = (id >> 3) & 63, ks = (id >> 9) & 15, t = (id >> 13) & 3, w = (id >> 15) & 3;
  int topic = t * 16 + (l & 15);
  int vocab = w * 512 + ks * 32 + (l >> 4) * 8 + e;
  VTp[id] = (topic < K_N && vocab < V_N) ? f2bf(1.0f / (float)V_N) : (unsigned short)0;
}

__global__ void finalize_kern(const float* __restrict__ accp, float* __restrict__ out) {
  if (threadIdx.x == 0)
    out[0] = (accp[0] + accp[1]) * (1.f / (float)B_N) + 0.1f * accp[2];
}

// ---------------------------------------------------------------------------
// Sinkhorn (R14/R17/R18 FROZEN): MLP sweep + distributed flags + per-wave
// group wait + bf16 fixed-point early exit (4-phase confirm, gated verdict).
// ---------------------------------------------------------------------------
__device__ __forceinline__ void sk_sweep(
    const bf16x8 (&Af)[16], const unsigned short* __restrict__ Xt,
    float* __restrict__ red, int wave, int lane) {
  const int m = lane & 15, q = lane >> 4;
  const unsigned short* xb = Xt + ((size_t)wave << 15) + lane * 8;
  bf16x8 Bv[4][16];
#pragma unroll
  for (int t = 0; t < 4; ++t)
#pragma unroll
    for (int ks = 0; ks < 16; ++ks)
      Bv[t][ks] = *(const bf16x8*)(xb + t * 8192 + ks * 512);
  __builtin_amdgcn_sched_barrier(0);
#pragma unroll
  for (int t = 0; t < 4; ++t) {
    f32x4n a = (f32x4n){0.f, 0.f, 0.f, 0.f};
#pragma unroll
    for (int ks = 0; ks < 16; ++ks)
      a = __builtin_amdgcn_mfma_f32_16x16x32_bf16(Af[ks], Bv[t][ks], a, 0, 0, 0);
    *(f32x4n*)&red[wave * 1280 + (t * 16 + m) * 20 + q * 4] = a;
  }
}

__device__ __forceinline__ void sk_sweep_km(
    const bf16x8 (&AfK)[16], const unsigned short* __restrict__ Xt,
    float* __restrict__ red, int wave, int lane) {
  const int m = lane & 15, q = lane >> 4;
  const unsigned short* xb = Xt + ((size_t)wave << 15) + lane * 8;
  bf16x8 Am[16];
#pragma unroll
  for (int ks = 0; ks < 16; ++ks) {
    union { bf16x8 v; unsigned short s[8]; } a, o;
    a.v = AfK[ks];
#pragma unroll
    for (int e = 0; e < 8; ++e) {
      float k = bf2f(a.s[e]);
      o.s[e] = (k > 0.f) ? f2bf(-0.1f * k * logf(k)) : (unsigned short)0;
    }
    Am[ks] = o.v;
  }
#pragma unroll
  for (int t = 0; t < 4; ++t) {
    f32x4n a = (f32x4n){0.f, 0.f, 0.f, 0.f};
#pragma unroll
    for (int ks = 0; ks < 16; ++ks) {
      bf16x8 bv = *(const bf16x8*)(xb + t * 8192 + ks * 512);
      a = __builtin_amdgcn_mfma_f32_16x16x32_bf16(Am[ks], bv, a, 0, 0, 0);
    }
    *(f32x4n*)&red[wave * 1280 + (t * 16 + m) * 20 + q * 4] = a;
  }
}

__global__ void __launch_bounds__(256, 1) sinkhorn_kern(
    const unsigned short* __restrict__ Kb, const unsigned short* __restrict__ KTb,
    const float* __restrict__ ATp, const float* __restrict__ BTp,
    unsigned short* __restrict__ ROTp, float* __restrict__ accp,
    int* __restrict__ flags) {
  __shared__ float red[5120];
  __shared__ int chgLDS[4];
  __shared__ int frzLDS[4];
  const int wg = (int)blockIdx.x, tid = threadIdx.x;
  const int wave = tid >> 6, lane = tid & 63;
  const int m = lane & 15, q = lane >> 4;

  bf16x8 AfK[16], AfT[16];
  {
    const unsigned short* arowK = Kb  + (size_t)(wg * 16 + m) * VP + wave * 512 + q * 8;
    const unsigned short* arowT = KTb + (size_t)(wg * 16 + m) * VP + wave * 512 + q * 8;
#pragma unroll
    for (int ks = 0; ks < 16; ++ks) {
      AfK[ks] = *(const bf16x8*)(arowK + ks * 32);
      AfT[ks] = *(const bf16x8*)(arowT + ks * 32);
    }
  }
  const int c = tid >> 2, r0 = (tid & 3) * 4;
  const f32x4n aA = *(const f32x4n*)(ATp + (size_t)c * VP + wg * 16 + r0);
  const f32x4n aB = *(const f32x4n*)(BTp + (size_t)c * VP + wg * 16 + r0);
  const int out_off = (((wg >> 5) * 4 + (c >> 4)) * 16 + ((wg & 31) >> 1)) * 512
                    + ((((wg & 1) << 1) | (r0 >> 3)) * 16 + (c & 15)) * 8 + (r0 & 7);

  int cnt8 = 0, sprev = 0;
  ushort4 pE = {0, 0, 0, 0}, pO = {0, 0, 0, 0};
  int lastph = 2 * SK_ITER - 1;

  for (int ph = 0; ph < 2 * SK_ITER; ++ph) {
    if (ph && (ph & 3) == 0) {
      __syncthreads();
      if (frzLDS[0] && frzLDS[1] && frzLDS[2] && frzLDS[3]) { lastph = ph - 1; break; }
    }
    const unsigned short* src = ROTp + (size_t)((ph + 31) & 31) * SLOT_E;
    unsigned short* dst = ROTp + (size_t)(ph & 31) * SLOT_E;
    if ((ph & 1) == 0) sk_sweep(AfK, src, red, wave, lane);
    else               sk_sweep(AfT, src, red, wave, lane);
    __syncthreads();
    {
      f32x4n s = (f32x4n){0.f, 0.f, 0.f, 0.f};
#pragma unroll
      for (int w = 0; w < 4; ++w) s += *(const f32x4n*)&red[w * 1280 + c * 20 + r0];
      f32x4n a4 = ((ph & 1) == 0) ? aA : aB;
      f32x4n u = a4 / (s + 1e-16f);
      ushort4 ub;
      ub.x = f2bf(u.x); ub.y = f2bf(u.y); ub.z = f2bf(u.z); ub.w = f2bf(u.w);
      ushort4 pv = (ph & 1) ? pO : pE;
      int changed = (ph < 2) ? 1 :
          ((((ub.x ^ pv.x) | (ub.y ^ pv.y)) | ((ub.z ^ pv.z) | (ub.w ^ pv.w))) != 0);
      if (ph & 1) pO = ub; else pE = ub;
      unsigned long long cb = __ballot(changed);
      if (lane == 0) chgLDS[wave] = (cb != 0ull) ? 1 : 0;
      coh_store8(dst + out_off, ub);
    }
    __syncthreads();
    if (tid == 0) {
      int changed_wg = chgLDS[0] | chgLDS[1] | chgLDS[2] | chgLDS[3];
      cnt8 = changed_wg ? 0 : (cnt8 + 1);
      int scur = (cnt8 >= 4) ? 1 : 0;
      __hip_atomic_store(&flags[wg * 32], ((ph + 1) << 2) | (scur << 1) | sprev,
                         __ATOMIC_RELAXED, __HIP_MEMORY_SCOPE_AGENT);
      sprev = scur;
    }
    {
      const int epoch = ph + 1;
      const int idx = (wave * 32 + (lane & 31)) * 32;
      int v = epoch << 2;
      int spin = 0;
      for (;;) {
        if (lane < 32)
          v = __hip_atomic_load(&flags[idx], __ATOMIC_RELAXED, __HIP_MEMORY_SCOPE_AGENT);
        if (__ballot((v >> 2) >= epoch) == ~0ull) break;
        __builtin_amdgcn_s_sleep(1);
        if (++spin >= (1 << 17)) break;
      }
      if ((epoch & 3) == 0) {   // verdict consumed only at next %4 break-check
        int frz = (lane < 32)
          ? (((v >> 2) == epoch) ? ((v >> 1) & 1) : (v & 1))
          : 1;
        unsigned long long fb = __ballot(frz != 0);
        if (lane == 0) frzLDS[wave] = (fb == ~0ull) ? 1 : 0;
      }
    }
  }

  const int lodd = (lastph & 1) ? lastph : (lastph - 1);
  const unsigned short* vfin = ROTp + (size_t)(lodd & 31) * SLOT_E;
  float u4[4];

  sk_sweep(AfK, vfin, red, wave, lane);
  __syncthreads();
  {
    f32x4n s = (f32x4n){0.f, 0.f, 0.f, 0.f};
#pragma unroll
    for (int w = 0; w < 4; ++w) s += *(const f32x4n*)&red[w * 1280 + c * 20 + r0];
#pragma unroll
    for (int i = 0; i < 4; ++i) u4[i] = aA[i] / (s[i] + 1e-16f);
  }
  __syncthreads();
  sk_sweep_km(AfK, vfin, red, wave, lane);
  __syncthreads();
  float part = 0.f;
  {
    f32x4n s = (f32x4n){0.f, 0.f, 0.f, 0.f};
#pragma unroll
    for (int w = 0; w < 4; ++w) s += *(const f32x4n*)&red[w * 1280 + c * 20 + r0];
#pragma unroll
    for (int i = 0; i < 4; ++i) part += u4[i] * s[i];
  }
  __syncthreads();
  red[tid] = part; __syncthreads();
  for (int st = 128; st; st >>= 1) { if (tid < st) red[tid] += red[tid + st]; __syncthreads(); }
  if (tid == 0) atomicAdd(accp + 2, red[0]);
}

// ---------------------------------------------------------------------------
extern "C" void kernel_launch(void* const* d_in, const int* in_sizes, int n_in,
                              void* d_out, int out_size, void* d_ws, size_t ws_size,
                              hipStream_t stream) {
  const float* x_a   = (const float*)d_in[0];
  const float* x_b   = (const float*)d_in[1];
  const float* eps_a = (const float*)d_in[2];
  const float* eps_b = (const float*)d_in[3];
  const float* W1_a  = (const float*)d_in[4];
  const float* b1_a  = (const float*)d_in[5];
  const float* W2_a  = (const float*)d_in[6];
  const float* b2_a  = (const float*)d_in[7];
  const float* Wmu_a = (const float*)d_in[8];
  const float* bmu_a = (const float*)d_in[9];
  const float* Wlv_a = (const float*)d_in[10];
  const float* blv_a = (const float*)d_in[11];
  const float* mbn_a = (const float*)d_in[12];
  const float* lbn_a = (const float*)d_in[13];
  const float* W1_b  = (const float*)d_in[14];
  const float* b1_b  = (const float*)d_in[15];
  const float* W2_b  = (const float*)d_in[16];
  const float* b2_b  = (const float*)d_in[17];
  const float* Wmu_b = (const float*)d_in[18];
  const float* bmu_b = (const float*)d_in[19];
  const float* Wlv_b = (const float*)d_in[20];
  const float* blv_b = (const float*)d_in[21];
  const float* mbn_b = (const float*)d_in[22];
  const float* lbn_b = (const float*)d_in[23];
  const float* dbn_a = (const float*)d_in[24];
  const float* dbn_b = (const float*)d_in[25];
  const float* phi_a = (const float*)d_in[26];
  const float* phi_b = (const float*)d_in[27];
  const float* bwe_a = (const float*)d_in[28];
  const float* bwe_b = (const float*)d_in[29];
  float* out = (float*)d_out;

  // ---- fused workspace layout (~37.9 MB; DEC overlays H1/H2) ----
  char* ws = (char*)d_ws;
  const size_t OFF_ACC  = 0;                      // 256 B
  const size_t OFF_BAR  = 256;                    // flags: 128 lines x 128 B
  const size_t OFF_ST   = OFF_BAR + 16384;        // stats block (196608 B)
  const size_t ST_SUM4  = OFF_ST;
  const size_t ST_SQ4   = ST_SUM4 + 32768;
  const size_t ST_MEAN4 = ST_SQ4 + 32768;
  const size_t ST_RSTD4 = ST_MEAN4 + 32768;
  const size_t ST_DSUM2 = ST_RSTD4 + 32768;
  const size_t ST_DSQ2  = ST_DSUM2 + 16384;
  const size_t ST_DMEAN2= ST_DSQ2 + 16384;
  const size_t ST_DRSTD2= ST_DMEAN2 + 16384;
  const size_t OFF_TH   = OFF_ST + 196608;
  const size_t OFF_MU   = OFF_TH + 1638400;
  const size_t OFF_LV   = OFF_MU + 1638400;
  const size_t OFF_BIG  = OFF_LV + 1638400;
  const size_t NEED     = OFF_BIG + 32768000;     // ~37.9 MB
  if (ws_size < NEED) return;

  float* ACCp = (float*)(ws + OFF_ACC);
  int*   FLGp = (int*)(ws + OFF_BAR);
  float* SUM4 = (float*)(ws + ST_SUM4);
  float* SQ4  = (float*)(ws + ST_SQ4);
  float* MEAN4= (float*)(ws + ST_MEAN4);
  float* RSTD4= (float*)(ws + ST_RSTD4);
  float* DSUM2= (float*)(ws + ST_DSUM2);
  float* DSQ2 = (float*)(ws + ST_DSQ2);
  float* DMEAN2=(float*)(ws + ST_DMEAN2);
  float* DRSTD2=(float*)(ws + ST_DRSTD2);
  float* THa  = (float*)(ws + OFF_TH);
  float* THb  = THa + 204800;
  float* MUa  = (float*)(ws + OFF_MU);
  float* MUb  = MUa + 204800;
  float* LVa  = (float*)(ws + OFF_LV);
  float* LVb  = LVa + 204800;
  float* H1a  = (float*)(ws + OFF_BIG);
  float* H1b  = H1a + 2048000;
  float* H2a  = H1b + 2048000;
  float* H2b  = H2a + 2048000;
  unsigned short* DECa = (unsigned short*)(ws + OFF_BIG);
  unsigned short* DECb = DECa + 8192000;
  // phase-2 overlay (KB|KT contiguous; AT|BT contiguous)
  float* NAp  = (float*)(ws + OFF_BIG);
  float* NBp  = (float*)(ws + OFF_BIG + 2400000);
  unsigned short* KBp = (unsigned short*)(ws + OFF_BIG + 4800000);
  unsigned short* KTp = (unsigned short*)(ws + OFF_BIG + 13188608);
  float* ATp  = (float*)(ws + OFF_BIG + 21577216);
  float* BTp  = (float*)(ws + OFF_BIG + 22101504);
  unsigned short* ROTp = (unsigned short*)(ws + OFF_BIG + 22625792);
  unsigned short* SLOT31 = ROTp + (size_t)31 * SLOT_E;

  hipMemsetAsync(ACCp, 0, 256, stream);
  hipMemsetAsync(FLGp, 0, 16384, stream);
  hipMemsetAsync((void*)(ws + OFF_ST), 0, 196608, stream);

  // ---- phase 1: both encoders fused via blockIdx.z (64-tile, XCD-swizzled) ----
  gemm_nn2_kern<<<dim3(8, 64, 2), 256, 0, stream>>>(
      x_a, W1_a, b1_a, H1a, x_b, W1_b, b1_b, H1b, B_N, H_N, V_N, 1, 0);
  gemm_nn2_kern<<<dim3(8, 64, 2), 256, 0, stream>>>(
      H1a, W2_a, b2_a, H2a, H1b, W2_b, b2_b, H2b, B_N, H_N, H_N, 1, 0);
  gemm_nn4_kern<<<dim3(1, 64, 4), 256, 0, stream>>>(
      H2a, Wmu_a, bmu_a, MUa,  H2a, Wlv_a, blv_a, LVa,
      H2b, Wmu_b, bmu_b, MUb,  H2b, Wlv_b, blv_b, LVb,
      B_N, K_N, H_N, 0, 0);
  colstats4_kern<<<dim3(1, 16, 4), 256, 0, stream>>>(MUa, LVa, MUb, LVb, K_N, 256, SUM4, SQ4);
  finstats_kern<<<32, 256, 0, stream>>>(SUM4, SQ4, 8192, 1.f / B_N, MEAN4, RSTD4);
  reparam2_kern<<<dim3(B_N / 4, 1, 2), 256, 0, stream>>>(
      MUa, LVa, MUb, LVb, MEAN4, RSTD4,
      mbn_a, lbn_a, mbn_b, lbn_b, eps_a, eps_b, THa, THb, ACCp);
  gemm_nn2_kern<<<dim3(32, 64, 2), 256, 0, stream>>>(
      THa, phi_a, nullptr, DECa, THb, phi_b, nullptr, DECb, B_N, V_N, K_N, 0, 1);
  colstats_bf2_kern<<<dim3(8, 16, 2), 256, 0, stream>>>(DECa, DECb, V_N, 256, DSUM2, DSQ2);
  finstats_kern<<<16, 256, 0, stream>>>(DSUM2, DSQ2, 4096, 1.f / B_N, DMEAN2, DRSTD2);
  decode_rec2_kern<<<dim3(B_N, 1, 2), 256, 0, stream>>>(
      DECa, DECb, DMEAN2, DRSTD2, dbn_a, dbn_b, x_a, x_b, ACCp);

  // ---- phase 2: Sinkhorn prep (overlays BIG; merged memsets) ----
  hipMemsetAsync(KBp, 0, 2 * (size_t)VP * VP * 2, stream);   // KB + KT (contiguous)
  hipMemsetAsync(ATp, 0, 2 * (size_t)TP * VP * 4, stream);   // AT + BT (contiguous)

  rownorm2_kern<<<dim3(V_N, 1, 2), 256, 0, stream>>>(bwe_a, NAp, bwe_b, NBp);
  gemm_nt_cost_kern<<<dim3(32, 32), 256, 0, stream>>>(NAp, NBp, KBp, KTp);
  topic_softmax2_kern<<<dim3(K_N, 1, 2), 256, 0, stream>>>(phi_a, ATp, phi_b, BTp);
  vinit_kern<<<SLOT_E / 256, 256, 0, stream>>>(SLOT31);

  // ---- Sinkhorn main loop (early exit, 4-phase confirm) ----
  sinkhorn_kern<<<dim3(SK_NWG), dim3(256), 0, stream>>>(KBp, KTp, ATp, BTp,
                                                        ROTp, ACCp, FLGp);

  finalize_kern<<<1, 64, 0, stream>>>(ACCp, out);
  (void)in_sizes; (void)n_in; (void)out_size;
}

// Round 14
// 1675.009 us; speedup vs baseline: 1.1707x; 1.0320x over previous
//
#include <hip/hip_runtime.h>

// Problem dims
#define B_N 4096
#define V_N 2000
#define K_N 50
#define H_N 500
#define E_N 300
#define VP  2048   // padded vocab (mult of 32 for MFMA k)
#define TP  64     // padded topics
#define SK_NWG 128
#define SK_ITER 500
#define SLOT_E (TP * VP)   // ushort elements per rotation slot (256 KB)

typedef short bf16x8 __attribute__((ext_vector_type(8)));
typedef float f32x4n __attribute__((ext_vector_type(4)));

__device__ __forceinline__ unsigned short f2bf(float f) {
  unsigned int x = __float_as_uint(f);
  x = (x + 0x7FFFu + ((x >> 16) & 1u)) >> 16;
  return (unsigned short)x;
}
__device__ __forceinline__ float bf2f(unsigned short h) {
  return __uint_as_float((unsigned int)h << 16);
}
__device__ __forceinline__ float softplusf(float x) {
  return fmaxf(x, 0.f) + log1pf(expf(-fabsf(x)));
}

// Agent-coherent 8B store (write-through to the coherence point).
__device__ __forceinline__ void coh_store8(unsigned short* p, ushort4 val) {
  union { ushort4 s; unsigned long long u; } cvt; cvt.s = val;
  __hip_atomic_store((unsigned long long*)p, cvt.u,
                     __ATOMIC_RELAXED, __HIP_MEMORY_SCOPE_AGENT);
}

// R18: bijective chunked XCD swizzle.
__device__ __forceinline__ void xcd_swizzle(int& bx, int& by, int& bz) {
  const int gx = (int)gridDim.x, gy = (int)gridDim.y;
  const int NB = gx * gy * (int)gridDim.z;
  const int lin = (int)blockIdx.x + gx * ((int)blockIdx.y + gy * (int)blockIdx.z);
  const int chunk = NB >> 3;
  const int lp = (lin & 7) * chunk + (lin >> 3);
  bx = lp % gx;
  const int tmp = lp / gx;
  by = tmp % gy;
  bz = tmp / gy;
}

// ---------------------------------------------------------------------------
// R21: 64x128-tile fp32 GEMM, acc[4][8]. The 64^2 GEMM is LDS-BW-bound
// (2 B/FMA; G1 floor ~238us vs 104us FMA). This tile reads 1.5 B/FMA
// (-25% LDS cycles). KEY: the 8-wide B read is split into two stride-16B
// float4 planes (Bs[16][136]: cols j<4 at [tx*4], j>=4 at [68+tx*4]) --
// both 2-way bank-aliased = FREE, avoiding the 4-way conflict (stride-32B
// reads) that silently ate R16's blocking gain. Occupancy: 512 blocks =
// 2 WG/CU = 2 waves/SIMD (midpoint; R16's 1 was fatal). LDS 25.5 KB.
// Per-output k-order ascending, guards exact no-ops -> BIT-IDENTICAL.
// ---------------------------------------------------------------------------
__device__ __forceinline__ void gemm_tile_body_w(
    const float* __restrict__ A, const float* __restrict__ Bm,
    const float* __restrict__ bias, void* __restrict__ Cv,
    int M, int N, int Kd, int act, int bf16out, int bx, int by,
    float (*As)[16][68], float (*Bs)[16][136]) {
  const int tid = threadIdx.x;
  const int tx = tid & 15, ty = tid >> 4;
  const int row0 = by * 64, col0 = bx * 128;
  const int bk = tid >> 4, bc = (tid & 15) * 8;   // B-stage: k-row, col0-of-8
  float acc[4][8];
#pragma unroll
  for (int i = 0; i < 4; ++i)
#pragma unroll
    for (int j = 0; j < 8; ++j) acc[i][j] = 0.f;

  float pa[4], pb[8];
  // prologue: tile 0
#pragma unroll
  for (int i = 0; i < 4; ++i) {
    int id = tid + 256 * i;
    int m = id >> 4, kk = id & 15;
    int gr = row0 + m;
    pa[i] = (gr < M && kk < Kd) ? A[(size_t)gr * Kd + kk] : 0.f;
  }
#pragma unroll
  for (int j = 0; j < 8; ++j) {
    int gc = col0 + bc + j;
    pb[j] = (bk < Kd && gc < N) ? Bm[(size_t)bk * N + gc] : 0.f;
  }
#pragma unroll
  for (int i = 0; i < 4; ++i) { int id = tid + 256 * i; As[0][id & 15][id >> 4] = pa[i]; }
#pragma unroll
  for (int j = 0; j < 4; ++j) Bs[0][bk][(bc >> 1) + j] = pb[j];          // tx*4 + j
#pragma unroll
  for (int j = 0; j < 4; ++j) Bs[0][bk][68 + (bc >> 1) + j] = pb[4 + j]; // split plane
  __syncthreads();

  const int nt = (Kd + 15) >> 4;
  for (int t = 1; t < nt; ++t) {
    const int k0 = t << 4;
#pragma unroll
    for (int i = 0; i < 4; ++i) {
      int id = tid + 256 * i;
      int m = id >> 4, kk = id & 15;
      int gr = row0 + m, gk = k0 + kk;
      pa[i] = (gr < M && gk < Kd) ? A[(size_t)gr * Kd + gk] : 0.f;
    }
#pragma unroll
    for (int j = 0; j < 8; ++j) {
      int gc = col0 + bc + j;
      pb[j] = (k0 + bk < Kd && gc < N) ? Bm[(size_t)(k0 + bk) * N + gc] : 0.f;
    }
    __builtin_amdgcn_sched_barrier(0);   // keep prefetch issued above FMAs
    const int cb = (t - 1) & 1;
#pragma unroll
    for (int kk = 0; kk < 16; ++kk) {
      float4 av = *(const float4*)&As[cb][kk][ty * 4];
      float4 b0 = *(const float4*)&Bs[cb][kk][tx * 4];
      float4 b1 = *(const float4*)&Bs[cb][kk][68 + tx * 4];
      float aa[4] = {av.x, av.y, av.z, av.w};
      float bb[8] = {b0.x, b0.y, b0.z, b0.w, b1.x, b1.y, b1.z, b1.w};
#pragma unroll
      for (int i = 0; i < 4; ++i)
#pragma unroll
        for (int j = 0; j < 8; ++j) acc[i][j] = fmaf(aa[i], bb[j], acc[i][j]);
    }
    const int wb = t & 1;
#pragma unroll
    for (int i = 0; i < 4; ++i) { int id = tid + 256 * i; As[wb][id & 15][id >> 4] = pa[i]; }
#pragma unroll
    for (int j = 0; j < 4; ++j) Bs[wb][bk][(bc >> 1) + j] = pb[j];
#pragma unroll
    for (int j = 0; j < 4; ++j) Bs[wb][bk][68 + (bc >> 1) + j] = pb[4 + j];
    __syncthreads();
  }
  const int lb = (nt - 1) & 1;
#pragma unroll
  for (int kk = 0; kk < 16; ++kk) {
    float4 av = *(const float4*)&As[lb][kk][ty * 4];
    float4 b0 = *(const float4*)&Bs[lb][kk][tx * 4];
    float4 b1 = *(const float4*)&Bs[lb][kk][68 + tx * 4];
    float aa[4] = {av.x, av.y, av.z, av.w};
    float bb[8] = {b0.x, b0.y, b0.z, b0.w, b1.x, b1.y, b1.z, b1.w};
#pragma unroll
    for (int i = 0; i < 4; ++i)
#pragma unroll
      for (int j = 0; j < 8; ++j) acc[i][j] = fmaf(aa[i], bb[j], acc[i][j]);
  }
#pragma unroll
  for (int i = 0; i < 4; ++i) {
    int row = row0 + ty * 4 + i;
    if (row >= M) continue;
#pragma unroll
    for (int j = 0; j < 8; ++j) {
      int col = col0 + tx * 8 + j;
      if (col >= N) continue;
      float v = acc[i][j] + (bias ? bias[col] : 0.f);
      if (act) v = softplusf(v);
      if (bf16out) ((unsigned short*)Cv)[(size_t)row * N + col] = f2bf(v);
      else         ((float*)Cv)[(size_t)row * N + col] = v;
    }
  }
}

// 2-way wide (z picks side a/b), XCD-swizzled
__global__ __launch_bounds__(256) void gemm_nn2w_kern(
    const float* A0, const float* B0, const float* b0, void* C0,
    const float* A1, const float* B1, const float* b1, void* C1,
    int M, int N, int Kd, int act, int bf16out) {
  __shared__ float As[2][16][68];
  __shared__ float Bs[2][16][136];
  int bx, by, bz;
  xcd_swizzle(bx, by, bz);
  gemm_tile_body_w(bz ? A1 : A0, bz ? B1 : B0, bz ? b1 : b0, bz ? C1 : C0,
                   M, N, Kd, act, bf16out, bx, by, As, Bs);
}

// ---------------------------------------------------------------------------
// 64-tile fp32 GEMM body (R15/R18) -- kept for the small mu/lv GEMM (N=50).
// ---------------------------------------------------------------------------
__device__ __forceinline__ void gemm_tile_body(
    const float* __restrict__ A, const float* __restrict__ Bm,
    const float* __restrict__ bias, void* __restrict__ Cv,
    int M, int N, int Kd, int act, int bf16out, int bx, int by,
    float (*As)[16][68], float (*Bs)[16][68]) {
  const int tid = threadIdx.x;
  const int tx = tid & 15, ty = tid >> 4;
  const int row0 = by * 64, col0 = bx * 64;
  float acc[4][4];
#pragma unroll
  for (int i = 0; i < 4; ++i)
#pragma unroll
    for (int j = 0; j < 4; ++j) acc[i][j] = 0.f;

  float pa[4], pb[4];
#pragma unroll
  for (int i = 0; i < 4; ++i) {
    int id = tid + 256 * i;
    int m = id >> 4, kk = id & 15;
    int gr = row0 + m;
    pa[i] = (gr < M && kk < Kd) ? A[(size_t)gr * Kd + kk] : 0.f;
  }
#pragma unroll
  for (int i = 0; i < 4; ++i) {
    int id = tid + 256 * i;
    int kk = id >> 6, n = id & 63;
    int gc = col0 + n;
    pb[i] = (kk < Kd && gc < N) ? Bm[(size_t)kk * N + gc] : 0.f;
  }
#pragma unroll
  for (int i = 0; i < 4; ++i) { int id = tid + 256 * i; As[0][id & 15][id >> 4] = pa[i]; }
#pragma unroll
  for (int i = 0; i < 4; ++i) { int id = tid + 256 * i; Bs[0][id >> 6][id & 63] = pb[i]; }
  __syncthreads();

  const int nt = (Kd + 15) >> 4;
  for (int t = 1; t < nt; ++t) {
    const int k0 = t << 4;
#pragma unroll
    for (int i = 0; i < 4; ++i) {
      int id = tid + 256 * i;
      int m = id >> 4, kk = id & 15;
      int gr = row0 + m, gk = k0 + kk;
      pa[i] = (gr < M && gk < Kd) ? A[(size_t)gr * Kd + gk] : 0.f;
    }
#pragma unroll
    for (int i = 0; i < 4; ++i) {
      int id = tid + 256 * i;
      int kk = id >> 6, n = id & 63;
      int gk = k0 + kk, gc = col0 + n;
      pb[i] = (gk < Kd && gc < N) ? Bm[(size_t)gk * N + gc] : 0.f;
    }
    __builtin_amdgcn_sched_barrier(0);
    const int cb = (t - 1) & 1;
#pragma unroll
    for (int kk = 0; kk < 16; ++kk) {
      float4 av = *(const float4*)&As[cb][kk][ty * 4];
      float4 bv = *(const float4*)&Bs[cb][kk][tx * 4];
      float aa[4] = {av.x, av.y, av.z, av.w};
      float bb[4] = {bv.x, bv.y, bv.z, bv.w};
#pragma unroll
      for (int i = 0; i < 4; ++i)
#pragma unroll
        for (int j = 0; j < 4; ++j) acc[i][j] = fmaf(aa[i], bb[j], acc[i][j]);
    }
    const int wb = t & 1;
#pragma unroll
    for (int i = 0; i < 4; ++i) { int id = tid + 256 * i; As[wb][id & 15][id >> 4] = pa[i]; }
#pragma unroll
    for (int i = 0; i < 4; ++i) { int id = tid + 256 * i; Bs[wb][id >> 6][id & 63] = pb[i]; }
    __syncthreads();
  }
  const int lb = (nt - 1) & 1;
#pragma unroll
  for (int kk = 0; kk < 16; ++kk) {
    float4 av = *(const float4*)&As[lb][kk][ty * 4];
    float4 bv = *(const float4*)&Bs[lb][kk][tx * 4];
    float aa[4] = {av.x, av.y, av.z, av.w};
    float bb[4] = {bv.x, bv.y, bv.z, bv.w};
#pragma unroll
    for (int i = 0; i < 4; ++i)
#pragma unroll
      for (int j = 0; j < 4; ++j) acc[i][j] = fmaf(aa[i], bb[j], acc[i][j]);
  }
#pragma unroll
  for (int i = 0; i < 4; ++i) {
    int row = row0 + ty * 4 + i;
    if (row >= M) continue;
#pragma unroll
    for (int j = 0; j < 4; ++j) {
      int col = col0 + tx * 4 + j;
      if (col >= N) continue;
      float v = acc[i][j] + (bias ? bias[col] : 0.f);
      if (act) v = softplusf(v);
      if (bf16out) ((unsigned short*)Cv)[(size_t)row * N + col] = f2bf(v);
      else         ((float*)Cv)[(size_t)row * N + col] = v;
    }
  }
}

// 4-way (mu_a, lv_a, mu_b, lv_b), XCD-swizzled
__global__ __launch_bounds__(256) void gemm_nn4_kern(
    const float* A0, const float* B0, const float* b0, void* C0,
    const float* A1, const float* B1, const float* b1, void* C1,
    const float* A2, const float* B2, const float* b2, void* C2,
    const float* A3, const float* B3, const float* b3, void* C3,
    int M, int N, int Kd, int act, int bf16out) {
  __shared__ float As[2][16][68];
  __shared__ float Bs[2][16][68];
  int bx, by, bz;
  xcd_swizzle(bx, by, bz);
  const float* A = (bz == 0) ? A0 : (bz == 1) ? A1 : (bz == 2) ? A2 : A3;
  const float* B = (bz == 0) ? B0 : (bz == 1) ? B1 : (bz == 2) ? B2 : B3;
  const float* bb = (bz == 0) ? b0 : (bz == 1) ? b1 : (bz == 2) ? b2 : b3;
  void* C = (bz == 0) ? C0 : (bz == 1) ? C1 : (bz == 2) ? C2 : C3;
  gemm_tile_body(A, B, bb, C, M, N, Kd, act, bf16out, bx, by, As, Bs);
}

// ---------------------------------------------------------------------------
// Column partial sums (BN stats) -- 4-way / 2-way fused
// ---------------------------------------------------------------------------
__global__ void colstats4_kern(
    const float* X0, const float* X1, const float* X2, const float* X3,
    int C, int rowsPer, float* __restrict__ sums, float* __restrict__ sumsq) {
  const int z = blockIdx.z;
  const float* X = (z == 0) ? X0 : (z == 1) ? X1 : (z == 2) ? X2 : X3;
  float* s_ = sums + (size_t)z * 2048;
  float* q_ = sumsq + (size_t)z * 2048;
  int c = (int)blockIdx.x * 256 + threadIdx.x;
  if (c >= C) return;
  int r0 = (int)blockIdx.y * rowsPer;
  float s = 0.f, s2 = 0.f;
  for (int r = r0; r < r0 + rowsPer; ++r) {
    float v = X[(size_t)r * C + c];
    s += v; s2 += v * v;
  }
  atomicAdd(&s_[c], s);
  atomicAdd(&q_[c], s2);
}

__global__ void colstats_bf2_kern(
    const unsigned short* X0, const unsigned short* X1,
    int C, int rowsPer, float* __restrict__ sums, float* __restrict__ sumsq) {
  const int z = blockIdx.z;
  const unsigned short* X = z ? X1 : X0;
  float* s_ = sums + (size_t)z * 2048;
  float* q_ = sumsq + (size_t)z * 2048;
  int c = (int)blockIdx.x * 256 + threadIdx.x;
  if (c >= C) return;
  int r0 = (int)blockIdx.y * rowsPer;
  float s = 0.f, s2 = 0.f;
  for (int r = r0; r < r0 + rowsPer; ++r) {
    float v = bf2f(X[(size_t)r * C + c]);
    s += v; s2 += v * v;
  }
  atomicAdd(&s_[c], s);
  atomicAdd(&q_[c], s2);
}

__global__ void finstats_kern(const float* __restrict__ sums, const float* __restrict__ sumsq,
                              int C, float invM, float* __restrict__ mean,
                              float* __restrict__ rstd) {
  int c = (int)blockIdx.x * 256 + threadIdx.x;
  if (c >= C) return;
  float mu = sums[c] * invM;
  float var = sumsq[c] * invM - mu * mu;
  mean[c] = mu;
  rstd[c] = rsqrtf(var + 1e-5f);
}

// ---------------------------------------------------------------------------
// BN-apply + reparam + row-softmax(50) -> theta ; accumulate KLD (2-way)
// ---------------------------------------------------------------------------
__global__ __launch_bounds__(256) void reparam2_kern(
    const float* __restrict__ MU0, const float* __restrict__ LV0,
    const float* __restrict__ MU1, const float* __restrict__ LV1,
    const float* __restrict__ mean4, const float* __restrict__ rstd4,
    const float* __restrict__ mbn0, const float* __restrict__ lbn0,
    const float* __restrict__ mbn1, const float* __restrict__ lbn1,
    const float* __restrict__ eps0, const float* __restrict__ eps1,
    float* __restrict__ TH0, float* __restrict__ TH1,
    float* __restrict__ accp) {
  const int z = blockIdx.z;
  const float* MUp = z ? MU1 : MU0;
  const float* LVp = z ? LV1 : LV0;
  const float* mmean = mean4 + (size_t)(z * 2) * 2048;
  const float* mrstd = rstd4 + (size_t)(z * 2) * 2048;
  const float* lmean = mean4 + (size_t)(z * 2 + 1) * 2048;
  const float* lrstd = rstd4 + (size_t)(z * 2 + 1) * 2048;
  const float* mbn = z ? mbn1 : mbn0;
  const float* lbn = z ? lbn1 : lbn0;
  const float* epsb = z ? eps1 : eps0;
  float* TH = z ? TH1 : TH0;

  const int wave = threadIdx.x >> 6, lane = threadIdx.x & 63;
  const int row = (int)blockIdx.x * 4 + wave;
  const bool act = lane < K_N;
  float mu = 0.f, lv = 0.f, zz = 0.f;
  size_t base = (size_t)row * K_N + lane;
  if (act) {
    mu = (MUp[base] - mmean[lane]) * mrstd[lane] + mbn[lane];
    lv = (LVp[base] - lmean[lane]) * lrstd[lane] + lbn[lane];
    zz = mu + expf(0.5f * lv) * epsb[base];
  }
  float zm = act ? zz : -1e30f;
#pragma unroll
  for (int m = 32; m; m >>= 1) zm = fmaxf(zm, __shfl_xor(zm, m));
  float e = act ? expf(zz - zm) : 0.f;
  float se = e;
#pragma unroll
  for (int m = 32; m; m >>= 1) se += __shfl_xor(se, m);
  if (act) TH[base] = e / se;
  float kt = 0.f;
  if (act) {
    float var = expf(lv);
    kt = var * (1.f / 0.98f) + mu * mu * (1.f / 0.98f) + logf(0.98f) - lv;
  }
  float sk = kt;
#pragma unroll
  for (int m = 32; m; m >>= 1) sk += __shfl_xor(sk, m);
  if (lane == 0) atomicAdd(accp + z, 0.5f * (sk - (float)K_N));
}

// ---------------------------------------------------------------------------
// decode: BN-apply + row softmax + rec; one block/row (2-way), single pass.
// ---------------------------------------------------------------------------
__global__ __launch_bounds__(256) void decode_rec2_kern(
    const unsigned short* __restrict__ D0, const unsigned short* __restrict__ D1,
    const float* __restrict__ mean2, const float* __restrict__ rstd2,
    const float* __restrict__ bias0, const float* __restrict__ bias1,
    const float* __restrict__ X0, const float* __restrict__ X1,
    float* __restrict__ accp) {
  __shared__ float sred[256];
  const int z = blockIdx.z;
  const unsigned short* DECb = z ? D1 : D0;
  const float* mean = mean2 + (size_t)z * 2048;
  const float* rstd = rstd2 + (size_t)z * 2048;
  const float* bias = z ? bias1 : bias0;
  const float* X = z ? X1 : X0;
  const int row = (int)blockIdx.x, tid = threadIdx.x;
  const size_t base = (size_t)row * V_N;

  float yv[8];
  float mx = -1e30f;
#pragma unroll
  for (int it = 0; it < 8; ++it) {
    int j = tid + it * 256;
    float y = -1e30f;
    if (j < V_N) y = (bf2f(DECb[base + j]) - mean[j]) * rstd[j] + bias[j];
    yv[it] = y;
    mx = fmaxf(mx, y);
  }
  sred[tid] = mx; __syncthreads();
  for (int s = 128; s; s >>= 1) { if (tid < s) sred[tid] = fmaxf(sred[tid], sred[tid + s]); __syncthreads(); }
  mx = sred[0]; __syncthreads();

  float ev[8];
  float se = 0.f;
#pragma unroll
  for (int it = 0; it < 8; ++it) {
    int j = tid + it * 256;
    float e = 0.f;
    if (j < V_N) { e = expf(yv[it] - mx); se += e; }
    ev[it] = e;
  }
  sred[tid] = se; __syncthreads();
  for (int s = 128; s; s >>= 1) { if (tid < s) sred[tid] += sred[tid + s]; __syncthreads(); }
  se = sred[0]; __syncthreads();

  float part = 0.f;
#pragma unroll
  for (int it = 0; it < 8; ++it) {
    int j = tid + it * 256;
    if (j < V_N) part += X[base + j] * logf(ev[it] / se + 1e-10f);
  }
  sred[tid] = part; __syncthreads();
  for (int s = 128; s; s >>= 1) { if (tid < s) sred[tid] += sred[tid + s]; __syncthreads(); }
  if (tid == 0) atomicAdd(accp + z, -sred[0]);
}

// ---------------------------------------------------------------------------
// Row L2-normalize (BWE -> na/nb), 2-way
// ---------------------------------------------------------------------------
__global__ void rownorm2_kern(const float* __restrict__ X0, float* __restrict__ Y0,
                              const float* __restrict__ X1, float* __restrict__ Y1) {
  __shared__ float sred[256];
  const int z = blockIdx.z;
  const float* Xp = z ? X1 : X0;
  float* Yp = z ? Y1 : Y0;
  const int row = (int)blockIdx.x, tid = threadIdx.x;
  float s = 0.f;
  for (int j = tid; j < E_N; j += 256) { float v = Xp[(size_t)row * E_N + j]; s += v * v; }
  sred[tid] = s; __syncthreads();
  for (int st = 128; st; st >>= 1) { if (tid < st) sred[tid] += sred[tid + st]; __syncthreads(); }
  float sc = 1.f / fmaxf(sqrtf(sred[0]), 1e-12f);
  for (int j = tid; j < E_N; j += 256) Yp[(size_t)row * E_N + j] = Xp[(size_t)row * E_N + j] * sc;
}

// ---------------------------------------------------------------------------
// M = 1 - na @ nb^T ; writes K=exp(-10M) and K^T as bf16 (VP-strided).
// XCD-swizzled (grid 32x32 = 1024, divisible by 8).
// ---------------------------------------------------------------------------
__global__ __launch_bounds__(256) void gemm_nt_cost_kern(
    const float* __restrict__ NAp, const float* __restrict__ NBp,
    unsigned short* __restrict__ Kb, unsigned short* __restrict__ KTb) {
  __shared__ float As[16][68];
  __shared__ float Bs[16][68];
  int bx, by, bz;
  xcd_swizzle(bx, by, bz);
  const int tid = threadIdx.x;
  const int tx = tid & 15, ty = tid >> 4;
  const int row0 = by * 64, col0 = bx * 64;
  float acc[4][4];
#pragma unroll
  for (int i = 0; i < 4; ++i)
#pragma unroll
    for (int j = 0; j < 4; ++j) acc[i][j] = 0.f;

  for (int e0 = 0; e0 < E_N; e0 += 16) {
#pragma unroll
    for (int i = 0; i < 4; ++i) {
      int id = tid + 256 * i;
      int m = id >> 4, e = id & 15;
      int ge = e0 + e;
      int gr = row0 + m;
      As[e][m] = (gr < V_N && ge < E_N) ? NAp[(size_t)gr * E_N + ge] : 0.f;
      int gc = col0 + m;
      Bs[e][m] = (gc < V_N && ge < E_N) ? NBp[(size_t)gc * E_N + ge] : 0.f;
    }
    __syncthreads();
#pragma unroll
    for (int kk = 0; kk < 16; ++kk) {
      float4 av = *(const float4*)&As[kk][ty * 4];
      float4 bv = *(const float4*)&Bs[kk][tx * 4];
      float aa[4] = {av.x, av.y, av.z, av.w};
      float bb[4] = {bv.x, bv.y, bv.z, bv.w};
#pragma unroll
      for (int i = 0; i < 4; ++i)
#pragma unroll
        for (int j = 0; j < 4; ++j) acc[i][j] = fmaf(aa[i], bb[j], acc[i][j]);
    }
    __syncthreads();
  }
#pragma unroll
  for (int i = 0; i < 4; ++i) {
    int gi = row0 + ty * 4 + i;
    if (gi >= V_N) continue;
#pragma unroll
    for (int j = 0; j < 4; ++j) {
      int gj = col0 + tx * 4 + j;
      if (gj >= V_N) continue;
      float m = 1.f - acc[i][j];
      float kv = expf(-10.f * m);
      Kb[(size_t)gi * VP + gj] = f2bf(kv);
      KTb[(size_t)gj * VP + gi] = f2bf(kv);
    }
  }
}

// ---------------------------------------------------------------------------
// a/b marginals: softmax over vocab of phi row t (f32, VP-strided), 2-way
// ---------------------------------------------------------------------------
__global__ void topic_softmax2_kern(const float* __restrict__ p0, float* __restrict__ A0,
                                    const float* __restrict__ p1, float* __restrict__ A1) {
  __shared__ float sred[256];
  const int z = blockIdx.z;
  const float* phi = z ? p1 : p0;
  float* ATp = z ? A1 : A0;
  const int t = (int)blockIdx.x, tid = threadIdx.x;
  const size_t base = (size_t)t * V_N;
  float mx = -1e30f;
  for (int i = tid; i < V_N; i += 256) mx = fmaxf(mx, phi[base + i]);
  sred[tid] = mx; __syncthreads();
  for (int s = 128; s; s >>= 1) { if (tid < s) sred[tid] = fmaxf(sred[tid], sred[tid + s]); __syncthreads(); }
  mx = sred[0]; __syncthreads();
  float se = 0.f;
  for (int i = tid; i < V_N; i += 256) se += expf(phi[base + i] - mx);
  sred[tid] = se; __syncthreads();
  for (int s = 128; s; s >>= 1) { if (tid < s) sred[tid] += sred[tid + s]; __syncthreads(); }
  se = sred[0];
  for (int i = tid; i < V_N; i += 256) ATp[(size_t)t * VP + i] = expf(phi[base + i] - mx) / se;
}

// ---------------------------------------------------------------------------
// Rotation slots live in MFMA-B-FRAGMENT order (coalesced consumer loads).
// ---------------------------------------------------------------------------
__global__ void vinit_kern(unsigned short* __restrict__ VTp) {
  int id = (int)blockIdx.x * 256 + threadIdx.x;
  if (id >= SLOT_E) return;
  int e = id & 7, l = (id >> 3) & 63, ks = (id >> 9) & 15, t = (id >> 13) & 3, w = (id >> 15) & 3;
  int topic = t * 16 + (l & 15);
  int vocab = w * 512 + ks * 32 + (l >> 4) * 8 + e;
  VTp[id] = (topic < K_N && vocab < V_N) ? f2bf(1.0f / (float)V_N) : (unsigned short)0;
}

__global__ void finalize_kern(const float* __restrict__ accp, float* __restrict__ out) {
  if (threadIdx.x == 0)
    out[0] = (accp[0] + accp[1]) * (1.f / (float)B_N) + 0.1f * accp[2];
}

// ---------------------------------------------------------------------------
// Sinkhorn (R14/R17/R18 FROZEN): MLP sweep + distributed flags + per-wave
// group wait + bf16 fixed-point early exit (4-phase confirm, gated verdict).
// ---------------------------------------------------------------------------
__device__ __forceinline__ void sk_sweep(
    const bf16x8 (&Af)[16], const unsigned short* __restrict__ Xt,
    float* __restrict__ red, int wave, int lane) {
  const int m = lane & 15, q = lane >> 4;
  const unsigned short* xb = Xt + ((size_t)wave << 15) + lane * 8;
  bf16x8 Bv[4][16];
#pragma unroll
  for (int t = 0; t < 4; ++t)
#pragma unroll
    for (int ks = 0; ks < 16; ++ks)
      Bv[t][ks] = *(const bf16x8*)(xb + t * 8192 + ks * 512);
  __builtin_amdgcn_sched_barrier(0);
#pragma unroll
  for (int t = 0; t < 4; ++t) {
    f32x4n a = (f32x4n){0.f, 0.f, 0.f, 0.f};
#pragma unroll
    for (int ks = 0; ks < 16; ++ks)
      a = __builtin_amdgcn_mfma_f32_16x16x32_bf16(Af[ks], Bv[t][ks], a, 0, 0, 0);
    *(f32x4n*)&red[wave * 1280 + (t * 16 + m) * 20 + q * 4] = a;
  }
}

__device__ __forceinline__ void sk_sweep_km(
    const bf16x8 (&AfK)[16], const unsigned short* __restrict__ Xt,
    float* __restrict__ red, int wave, int lane) {
  const int m = lane & 15, q = lane >> 4;
  const unsigned short* xb = Xt + ((size_t)wave << 15) + lane * 8;
  bf16x8 Am[16];
#pragma unroll
  for (int ks = 0; ks < 16; ++ks) {
    union { bf16x8 v; unsigned short s[8]; } a, o;
    a.v = AfK[ks];
#pragma unroll
    for (int e = 0; e < 8; ++e) {
      float k = bf2f(a.s[e]);
      o.s[e] = (k > 0.f) ? f2bf(-0.1f * k * logf(k)) : (unsigned short)0;
    }
    Am[ks] = o.v;
  }
#pragma unroll
  for (int t = 0; t < 4; ++t) {
    f32x4n a = (f32x4n){0.f, 0.f, 0.f, 0.f};
#pragma unroll
    for (int ks = 0; ks < 16; ++ks) {
      bf16x8 bv = *(const bf16x8*)(xb + t * 8192 + ks * 512);
      a = __builtin_amdgcn_mfma_f32_16x16x32_bf16(Am[ks], bv, a, 0, 0, 0);
    }
    *(f32x4n*)&red[wave * 1280 + (t * 16 + m) * 20 + q * 4] = a;
  }
}

__global__ void __launch_bounds__(256, 1) sinkhorn_kern(
    const unsigned short* __restrict__ Kb, const unsigned short* __restrict__ KTb,
    const float* __restrict__ ATp, const float* __restrict__ BTp,
    unsigned short* __restrict__ ROTp, float* __restrict__ accp,
    int* __restrict__ flags) {
  __shared__ float red[5120];
  __shared__ int chgLDS[4];
  __shared__ int frzLDS[4];
  const int wg = (int)blockIdx.x, tid = threadIdx.x;
  const int wave = tid >> 6, lane = tid & 63;
  const int m = lane & 15, q = lane >> 4;

  bf16x8 AfK[16], AfT[16];
  {
    const unsigned short* arowK = Kb  + (size_t)(wg * 16 + m) * VP + wave * 512 + q * 8;
    const unsigned short* arowT = KTb + (size_t)(wg * 16 + m) * VP + wave * 512 + q * 8;
#pragma unroll
    for (int ks = 0; ks < 16; ++ks) {
      AfK[ks] = *(const bf16x8*)(arowK + ks * 32);
      AfT[ks] = *(const bf16x8*)(arowT + ks * 32);
    }
  }
  const int c = tid >> 2, r0 = (tid & 3) * 4;
  const f32x4n aA = *(const f32x4n*)(ATp + (size_t)c * VP + wg * 16 + r0);
  const f32x4n aB = *(const f32x4n*)(BTp + (size_t)c * VP + wg * 16 + r0);
  const int out_off = (((wg >> 5) * 4 + (c >> 4)) * 16 + ((wg & 31) >> 1)) * 512
                    + ((((wg & 1) << 1) | (r0 >> 3)) * 16 + (c & 15)) * 8 + (r0 & 7);

  int cnt8 = 0, sprev = 0;
  ushort4 pE = {0, 0, 0, 0}, pO = {0, 0, 0, 0};
  int lastph = 2 * SK_ITER - 1;

  for (int ph = 0; ph < 2 * SK_ITER; ++ph) {
    if (ph && (ph & 3) == 0) {
      __syncthreads();
      if (frzLDS[0] && frzLDS[1] && frzLDS[2] && frzLDS[3]) { lastph = ph - 1; break; }
    }
    const unsigned short* src = ROTp + (size_t)((ph + 31) & 31) * SLOT_E;
    unsigned short* dst = ROTp + (size_t)(ph & 31) * SLOT_E;
    if ((ph & 1) == 0) sk_sweep(AfK, src, red, wave, lane);
    else               sk_sweep(AfT, src, red, wave, lane);
    __syncthreads();
    {
      f32x4n s = (f32x4n){0.f, 0.f, 0.f, 0.f};
#pragma unroll
      for (int w = 0; w < 4; ++w) s += *(const f32x4n*)&red[w * 1280 + c * 20 + r0];
      f32x4n a4 = ((ph & 1) == 0) ? aA : aB;
      f32x4n u = a4 / (s + 1e-16f);
      ushort4 ub;
      ub.x = f2bf(u.x); ub.y = f2bf(u.y); ub.z = f2bf(u.z); ub.w = f2bf(u.w);
      ushort4 pv = (ph & 1) ? pO : pE;
      int changed = (ph < 2) ? 1 :
          ((((ub.x ^ pv.x) | (ub.y ^ pv.y)) | ((ub.z ^ pv.z) | (ub.w ^ pv.w))) != 0);
      if (ph & 1) pO = ub; else pE = ub;
      unsigned long long cb = __ballot(changed);
      if (lane == 0) chgLDS[wave] = (cb != 0ull) ? 1 : 0;
      coh_store8(dst + out_off, ub);
    }
    __syncthreads();
    if (tid == 0) {
      int changed_wg = chgLDS[0] | chgLDS[1] | chgLDS[2] | chgLDS[3];
      cnt8 = changed_wg ? 0 : (cnt8 + 1);
      int scur = (cnt8 >= 4) ? 1 : 0;
      __hip_atomic_store(&flags[wg * 32], ((ph + 1) << 2) | (scur << 1) | sprev,
                         __ATOMIC_RELAXED, __HIP_MEMORY_SCOPE_AGENT);
      sprev = scur;
    }
    {
      const int epoch = ph + 1;
      const int idx = (wave * 32 + (lane & 31)) * 32;
      int v = epoch << 2;
      int spin = 0;
      for (;;) {
        if (lane < 32)
          v = __hip_atomic_load(&flags[idx], __ATOMIC_RELAXED, __HIP_MEMORY_SCOPE_AGENT);
        if (__ballot((v >> 2) >= epoch) == ~0ull) break;
        __builtin_amdgcn_s_sleep(1);
        if (++spin >= (1 << 17)) break;
      }
      if ((epoch & 3) == 0) {   // verdict consumed only at next %4 break-check
        int frz = (lane < 32)
          ? (((v >> 2) == epoch) ? ((v >> 1) & 1) : (v & 1))
          : 1;
        unsigned long long fb = __ballot(frz != 0);
        if (lane == 0) frzLDS[wave] = (fb == ~0ull) ? 1 : 0;
      }
    }
  }

  const int lodd = (lastph & 1) ? lastph : (lastph - 1);
  const unsigned short* vfin = ROTp + (size_t)(lodd & 31) * SLOT_E;
  float u4[4];

  sk_sweep(AfK, vfin, red, wave, lane);
  __syncthreads();
  {
    f32x4n s = (f32x4n){0.f, 0.f, 0.f, 0.f};
#pragma unroll
    for (int w = 0; w < 4; ++w) s += *(const f32x4n*)&red[w * 1280 + c * 20 + r0];
#pragma unroll
    for (int i = 0; i < 4; ++i) u4[i] = aA[i] / (s[i] + 1e-16f);
  }
  __syncthreads();
  sk_sweep_km(AfK, vfin, red, wave, lane);
  __syncthreads();
  float part = 0.f;
  {
    f32x4n s = (f32x4n){0.f, 0.f, 0.f, 0.f};
#pragma unroll
    for (int w = 0; w < 4; ++w) s += *(const f32x4n*)&red[w * 1280 + c * 20 + r0];
#pragma unroll
    for (int i = 0; i < 4; ++i) part += u4[i] * s[i];
  }
  __syncthreads();
  red[tid] = part; __syncthreads();
  for (int st = 128; st; st >>= 1) { if (tid < st) red[tid] += red[tid + st]; __syncthreads(); }
  if (tid == 0) atomicAdd(accp + 2, red[0]);
}

// ---------------------------------------------------------------------------
extern "C" void kernel_launch(void* const* d_in, const int* in_sizes, int n_in,
                              void* d_out, int out_size, void* d_ws, size_t ws_size,
                              hipStream_t stream) {
  const float* x_a   = (const float*)d_in[0];
  const float* x_b   = (const float*)d_in[1];
  const float* eps_a = (const float*)d_in[2];
  const float* eps_b = (const float*)d_in[3];
  const float* W1_a  = (const float*)d_in[4];
  const float* b1_a  = (const float*)d_in[5];
  const float* W2_a  = (const float*)d_in[6];
  const float* b2_a  = (const float*)d_in[7];
  const float* Wmu_a = (const float*)d_in[8];
  const float* bmu_a = (const float*)d_in[9];
  const float* Wlv_a = (const float*)d_in[10];
  const float* blv_a = (const float*)d_in[11];
  const float* mbn_a = (const float*)d_in[12];
  const float* lbn_a = (const float*)d_in[13];
  const float* W1_b  = (const float*)d_in[14];
  const float* b1_b  = (const float*)d_in[15];
  const float* W2_b  = (const float*)d_in[16];
  const float* b2_b  = (const float*)d_in[17];
  const float* Wmu_b = (const float*)d_in[18];
  const float* bmu_b = (const float*)d_in[19];
  const float* Wlv_b = (const float*)d_in[20];
  const float* blv_b = (const float*)d_in[21];
  const float* mbn_b = (const float*)d_in[22];
  const float* lbn_b = (const float*)d_in[23];
  const float* dbn_a = (const float*)d_in[24];
  const float* dbn_b = (const float*)d_in[25];
  const float* phi_a = (const float*)d_in[26];
  const float* phi_b = (const float*)d_in[27];
  const float* bwe_a = (const float*)d_in[28];
  const float* bwe_b = (const float*)d_in[29];
  float* out = (float*)d_out;

  // ---- fused workspace layout (~37.9 MB; DEC overlays H1/H2) ----
  char* ws = (char*)d_ws;
  const size_t OFF_ACC  = 0;                      // 256 B
  const size_t OFF_BAR  = 256;                    // flags: 128 lines x 128 B
  const size_t OFF_ST   = OFF_BAR + 16384;        // stats block (196608 B)
  const size_t ST_SUM4  = OFF_ST;
  const size_t ST_SQ4   = ST_SUM4 + 32768;
  const size_t ST_MEAN4 = ST_SQ4 + 32768;
  const size_t ST_RSTD4 = ST_MEAN4 + 32768;
  const size_t ST_DSUM2 = ST_RSTD4 + 32768;
  const size_t ST_DSQ2  = ST_DSUM2 + 16384;
  const size_t ST_DMEAN2= ST_DSQ2 + 16384;
  const size_t ST_DRSTD2= ST_DMEAN2 + 16384;
  const size_t OFF_TH   = OFF_ST + 196608;
  const size_t OFF_MU   = OFF_TH + 1638400;
  const size_t OFF_LV   = OFF_MU + 1638400;
  const size_t OFF_BIG  = OFF_LV + 1638400;
  const size_t NEED     = OFF_BIG + 32768000;     // ~37.9 MB
  if (ws_size < NEED) return;

  float* ACCp = (float*)(ws + OFF_ACC);
  int*   FLGp = (int*)(ws + OFF_BAR);
  float* SUM4 = (float*)(ws + ST_SUM4);
  float* SQ4  = (float*)(ws + ST_SQ4);
  float* MEAN4= (float*)(ws + ST_MEAN4);
  float* RSTD4= (float*)(ws + ST_RSTD4);
  float* DSUM2= (float*)(ws + ST_DSUM2);
  float* DSQ2 = (float*)(ws + ST_DSQ2);
  float* DMEAN2=(float*)(ws + ST_DMEAN2);
  float* DRSTD2=(float*)(ws + ST_DRSTD2);
  float* THa  = (float*)(ws + OFF_TH);
  float* THb  = THa + 204800;
  float* MUa  = (float*)(ws + OFF_MU);
  float* MUb  = MUa + 204800;
  float* LVa  = (float*)(ws + OFF_LV);
  float* LVb  = LVa + 204800;
  float* H1a  = (float*)(ws + OFF_BIG);
  float* H1b  = H1a + 2048000;
  float* H2a  = H1b + 2048000;
  float* H2b  = H2a + 2048000;
  unsigned short* DECa = (unsigned short*)(ws + OFF_BIG);
  unsigned short* DECb = DECa + 8192000;
  // phase-2 overlay (KB|KT contiguous; AT|BT contiguous)
  float* NAp  = (float*)(ws + OFF_BIG);
  float* NBp  = (float*)(ws + OFF_BIG + 2400000);
  unsigned short* KBp = (unsigned short*)(ws + OFF_BIG + 4800000);
  unsigned short* KTp = (unsigned short*)(ws + OFF_BIG + 13188608);
  float* ATp  = (float*)(ws + OFF_BIG + 21577216);
  float* BTp  = (float*)(ws + OFF_BIG + 22101504);
  unsigned short* ROTp = (unsigned short*)(ws + OFF_BIG + 22625792);
  unsigned short* SLOT31 = ROTp + (size_t)31 * SLOT_E;

  hipMemsetAsync(ACCp, 0, 256, stream);
  hipMemsetAsync(FLGp, 0, 16384, stream);
  hipMemsetAsync((void*)(ws + OFF_ST), 0, 196608, stream);

  // ---- phase 1: both encoders fused via blockIdx.z; big GEMMs 64x128 ----
  gemm_nn2w_kern<<<dim3(4, 64, 2), 256, 0, stream>>>(
      x_a, W1_a, b1_a, H1a, x_b, W1_b, b1_b, H1b, B_N, H_N, V_N, 1, 0);
  gemm_nn2w_kern<<<dim3(4, 64, 2), 256, 0, stream>>>(
      H1a, W2_a, b2_a, H2a, H1b, W2_b, b2_b, H2b, B_N, H_N, H_N, 1, 0);
  gemm_nn4_kern<<<dim3(1, 64, 4), 256, 0, stream>>>(
      H2a, Wmu_a, bmu_a, MUa,  H2a, Wlv_a, blv_a, LVa,
      H2b, Wmu_b, bmu_b, MUb,  H2b, Wlv_b, blv_b, LVb,
      B_N, K_N, H_N, 0, 0);
  colstats4_kern<<<dim3(1, 16, 4), 256, 0, stream>>>(MUa, LVa, MUb, LVb, K_N, 256, SUM4, SQ4);
  finstats_kern<<<32, 256, 0, stream>>>(SUM4, SQ4, 8192, 1.f / B_N, MEAN4, RSTD4);
  reparam2_kern<<<dim3(B_N / 4, 1, 2), 256, 0, stream>>>(
      MUa, LVa, MUb, LVb, MEAN4, RSTD4,
      mbn_a, lbn_a, mbn_b, lbn_b, eps_a, eps_b, THa, THb, ACCp);
  gemm_nn2w_kern<<<dim3(16, 64, 2), 256, 0, stream>>>(
      THa, phi_a, nullptr, DECa, THb, phi_b, nullptr, DECb, B_N, V_N, K_N, 0, 1);
  colstats_bf2_kern<<<dim3(8, 16, 2), 256, 0, stream>>>(DECa, DECb, V_N, 256, DSUM2, DSQ2);
  finstats_kern<<<16, 256, 0, stream>>>(DSUM2, DSQ2, 4096, 1.f / B_N, DMEAN2, DRSTD2);
  decode_rec2_kern<<<dim3(B_N, 1, 2), 256, 0, stream>>>(
      DECa, DECb, DMEAN2, DRSTD2, dbn_a, dbn_b, x_a, x_b, ACCp);

  // ---- phase 2: Sinkhorn prep (overlays BIG; merged memsets) ----
  hipMemsetAsync(KBp, 0, 2 * (size_t)VP * VP * 2, stream);   // KB + KT (contiguous)
  hipMemsetAsync(ATp, 0, 2 * (size_t)TP * VP * 4, stream);   // AT + BT (contiguous)

  rownorm2_kern<<<dim3(V_N, 1, 2), 256, 0, stream>>>(bwe_a, NAp, bwe_b, NBp);
  gemm_nt_cost_kern<<<dim3(32, 32), 256, 0, stream>>>(NAp, NBp, KBp, KTp);
  topic_softmax2_kern<<<dim3(K_N, 1, 2), 256, 0, stream>>>(phi_a, ATp, phi_b, BTp);
  vinit_kern<<<SLOT_E / 256, 256, 0, stream>>>(SLOT31);

  // ---- Sinkhorn main loop (early exit, 4-phase confirm) ----
  sinkhorn_kern<<<dim3(SK_NWG), dim3(256), 0, stream>>>(KBp, KTp, ATp, BTp,
                                                        ROTp, ACCp, FLGp);

  finalize_kern<<<1, 64, 0, stream>>>(ACCp, out);
  (void)in_sizes; (void)n_in; (void)out_size;
}